// Round 5
// baseline (3953.723 us; speedup 1.0000x reference)
//
#include <hip/hip_runtime.h>

// ---------------------------------------------------------------------------
// BISECT ROUND: MFMA gemm1 + RoPE(f64 trig) + *scalar fp32 VALU attention* +
// MFMA gemm2.  Attention is the only piece changed vs round 4 — if the 1.068
// absmax persists, the MFMA attention core is exonerated; if it passes, the
// bug is localized there.
// B=2, T=2048, C=1024, H=16, HD=64.  I/O fp32; internal tensors bf16.
// ---------------------------------------------------------------------------

typedef __attribute__((ext_vector_type(8))) short short8;   // 8 bf16 = 4 VGPRs
typedef __attribute__((ext_vector_type(4))) float floatx4;  // MFMA C/D frag

__device__ __forceinline__ ushort f2bf(float f) {
    unsigned x = __float_as_uint(f);
    x += 0x7fffu + ((x >> 16) & 1u);   // round-to-nearest-even
    return (ushort)(x >> 16);
}
__device__ __forceinline__ float bf2f(ushort u) {
    return __uint_as_float(((unsigned)u) << 16);
}

#define MFMA16(a, b, c) __builtin_amdgcn_mfma_f32_16x16x32_bf16((a), (b), (c), 0, 0, 0)

// ---------------------------------------------------------------------------
// GEMM1 (one batch): qkv = x_b[2048][1024](f32) @ W_attn[1024][3072](f32) ->
//   q: [H,T,HD]   k: [H,T,HD]   v^T: [H,HD,T]   (bf16)
// ---------------------------------------------------------------------------
__global__ __launch_bounds__(256, 2) void gemm1_qkv_k(const float* __restrict__ A,
                                                      const float* __restrict__ Bw,
                                                      ushort* __restrict__ qb,
                                                      ushort* __restrict__ kb,
                                                      ushort* __restrict__ vtb) {
    __shared__ __align__(16) ushort As[128][40];   // As[m][k]
    __shared__ __align__(16) ushort Bs[128][40];   // Bs[n][k]
    const int tid = threadIdx.x;
    const int m0 = blockIdx.y * 128, n0 = blockIdx.x * 128;
    const int w = tid >> 6, lane = tid & 63, quad = lane >> 4, l16 = lane & 15;
    const int wr = w >> 1, wc = w & 1;
    const int K = 1024, N = 3072;

    floatx4 acc[4][4];
#pragma unroll
    for (int mt = 0; mt < 4; mt++)
#pragma unroll
        for (int nt = 0; nt < 4; nt++) acc[mt][nt] = (floatx4){0.f, 0.f, 0.f, 0.f};

    for (int k0 = 0; k0 < K; k0 += 32) {
        __syncthreads();
#pragma unroll
        for (int j = 0; j < 4; j++) {
            int flat = (tid + j * 256) * 4;
            int r = flat >> 5, c = flat & 31;
            float4 t4 = *(const float4*)&A[(size_t)(m0 + r) * K + k0 + c];
            ushort4 u4 = make_ushort4(f2bf(t4.x), f2bf(t4.y), f2bf(t4.z), f2bf(t4.w));
            *(ushort4*)&As[r][c] = u4;
        }
#pragma unroll
        for (int j = 0; j < 4; j++) {
            int flat = (tid + j * 256) * 4;
            int bk = flat >> 7, bn = flat & 127;
            float4 t4 = *(const float4*)&Bw[(size_t)(k0 + bk) * N + n0 + bn];
            Bs[bn + 0][bk] = f2bf(t4.x);
            Bs[bn + 1][bk] = f2bf(t4.y);
            Bs[bn + 2][bk] = f2bf(t4.z);
            Bs[bn + 3][bk] = f2bf(t4.w);
        }
        __syncthreads();
        short8 af[4], bfr[4];
#pragma unroll
        for (int mt = 0; mt < 4; mt++) af[mt] = *(short8*)&As[wr * 64 + mt * 16 + l16][quad * 8];
#pragma unroll
        for (int nt = 0; nt < 4; nt++) bfr[nt] = *(short8*)&Bs[wc * 64 + nt * 16 + l16][quad * 8];
#pragma unroll
        for (int mt = 0; mt < 4; mt++)
#pragma unroll
            for (int nt = 0; nt < 4; nt++) acc[mt][nt] = MFMA16(af[mt], bfr[nt], acc[mt][nt]);
    }

#pragma unroll
    for (int nt = 0; nt < 4; nt++) {
        const int n = n0 + wc * 64 + nt * 16 + l16;
        const int seg = n >> 10;          // 0=q 1=k 2=v
        const int cn = n & 1023;
        const int h = cn >> 6, d = cn & 63;
#pragma unroll
        for (int mt = 0; mt < 4; mt++) {
#pragma unroll
            for (int r = 0; r < 4; r++) {
                const int t = m0 + wr * 64 + mt * 16 + quad * 4 + r;
                const ushort v = f2bf(acc[mt][nt][r]);
                if (seg == 0)      qb[((size_t)h * 2048 + t) * 64 + d] = v;
                else if (seg == 1) kb[((size_t)h * 2048 + t) * 64 + d] = v;
                else               vtb[((size_t)h * 64 + d) * 2048 + t] = v;
            }
        }
    }
}

// ---------------------------------------------------------------------------
// RoPE (roll variant), float64 trig: x[d]*cos + x[(d-1)&63]*sin, in-place.
// ---------------------------------------------------------------------------
__global__ __launch_bounds__(256) void rope_k(ushort* __restrict__ q, ushort* __restrict__ k) {
    const int wid = blockIdx.x * 4 + (threadIdx.x >> 6);  // row = h*2048 + t
    const int lane = threadIdx.x & 63;
    const int t = wid & 2047;
    const int j = lane & 31;
    const double inv = pow(10000.0, -(double)j / 32.0);
    const double ang = (double)t * inv;
    const float c = (float)cos(ang);
    const float s = (float)sin(ang);
    const size_t base = (size_t)wid * 64;

    float qv = bf2f(q[base + lane]);
    float qp = __shfl(qv, (lane + 63) & 63, 64);
    q[base + lane] = f2bf(qv * c + qp * s);

    float kv = bf2f(k[base + lane]);
    float kp = __shfl(kv, (lane + 63) & 63, 64);
    k[base + lane] = f2bf(kv * c + kp * s);
}

// ---------------------------------------------------------------------------
// VALU flash attention probe (exact fp32 math, causal).  Block = (h, 64-row
// q-tile), 64 threads; thread i owns q-row q0+i.  K/V tiles staged to LDS as
// fp32; per-thread exact online softmax; scores parked in LDS (Ss).
// Output y [T,C] row-major bf16.
// ---------------------------------------------------------------------------
__global__ __launch_bounds__(64) void attn_valu_k(const ushort* __restrict__ q,
                                                  const ushort* __restrict__ k,
                                                  const ushort* __restrict__ vt,
                                                  ushort* __restrict__ y) {
    __shared__ float Ks[64][65];   // [key][d]
    __shared__ float Vs[64][65];   // [key][d]
    __shared__ float Ss[64][65];   // [thread][key] score scratch

    const int qt = blockIdx.x & 31;
    const int h = blockIdx.x >> 5;
    const int i = threadIdx.x;     // 0..63
    const int q0 = qt * 64;

    float qreg[64], O[64];
    {
        const ushort* qp = q + ((size_t)h * 2048 + q0 + i) * 64;
#pragma unroll
        for (int d = 0; d < 64; d++) { qreg[d] = bf2f(qp[d]); O[d] = 0.f; }
    }
    float M = -3e4f, L = 0.f;

    for (int kt = 0; kt <= qt; kt++) {
        const int kbase = kt * 64;
        __syncthreads();
        // thread i stages K row kbase+i and V key kbase+i
#pragma unroll
        for (int d = 0; d < 64; d++)
            Ks[i][d] = bf2f(k[((size_t)h * 2048 + kbase + i) * 64 + d]);
#pragma unroll
        for (int d = 0; d < 64; d++)
            Vs[i][d] = bf2f(vt[((size_t)h * 64 + d) * 2048 + kbase + i]);
        __syncthreads();

        const bool diag = (kt == qt);
        float mx = -3e4f;
        for (int n = 0; n < 64; n++) {
            float acc = 0.f;
#pragma unroll
            for (int d = 0; d < 64; d++) acc += qreg[d] * Ks[n][d];
            acc *= 0.125f;                       // 1/sqrt(64)
            if (diag && n > i) acc = -3e4f;      // causal: key q0+n > q-row q0+i
            Ss[i][n] = acc;
            mx = fmaxf(mx, acc);
        }
        const float Mn = fmaxf(M, mx);
        const float alpha = __expf(M - Mn);
        float sum = 0.f;
        for (int n = 0; n < 64; n++) {
            float p = __expf(Ss[i][n] - Mn);
            Ss[i][n] = p;
            sum += p;
        }
        L = L * alpha + sum;
        M = Mn;
#pragma unroll
        for (int d = 0; d < 64; d++) O[d] *= alpha;
        for (int n = 0; n < 64; n++) {
            const float p = Ss[i][n];
#pragma unroll
            for (int d = 0; d < 64; d++) O[d] += p * Vs[n][d];
        }
    }

    ushort* yp = y + (size_t)(q0 + i) * 1024 + h * 64;
    const float rl = 1.0f / L;
#pragma unroll
    for (int d = 0; d < 64; d++) yp[d] = f2bf(O[d] * rl);
}

// ---------------------------------------------------------------------------
// GEMM2 (one batch): out(f32) = y[2048][1024](bf16) @ W_proj[1024][1024](f32)
// ---------------------------------------------------------------------------
__global__ __launch_bounds__(256, 2) void gemm2_proj_k(const ushort* __restrict__ Y,
                                                       const float* __restrict__ Bw,
                                                       float* __restrict__ out) {
    __shared__ __align__(16) ushort As[128][40];
    __shared__ __align__(16) ushort Bs[128][40];
    const int tid = threadIdx.x;
    const int m0 = blockIdx.y * 128, n0 = blockIdx.x * 128;
    const int w = tid >> 6, lane = tid & 63, quad = lane >> 4, l16 = lane & 15;
    const int wr = w >> 1, wc = w & 1;
    const int K = 1024, N = 1024;

    floatx4 acc[4][4];
#pragma unroll
    for (int mt = 0; mt < 4; mt++)
#pragma unroll
        for (int nt = 0; nt < 4; nt++) acc[mt][nt] = (floatx4){0.f, 0.f, 0.f, 0.f};

    for (int k0 = 0; k0 < K; k0 += 32) {
        __syncthreads();
#pragma unroll
        for (int j = 0; j < 2; j++) {
            int flat = (tid + j * 256) * 8;
            int r = flat >> 5, c = flat & 31;
            *(uint4*)&As[r][c] = *(const uint4*)&Y[(size_t)(m0 + r) * K + k0 + c];
        }
#pragma unroll
        for (int j = 0; j < 4; j++) {
            int flat = (tid + j * 256) * 4;
            int bk = flat >> 7, bn = flat & 127;
            float4 t4 = *(const float4*)&Bw[(size_t)(k0 + bk) * N + n0 + bn];
            Bs[bn + 0][bk] = f2bf(t4.x);
            Bs[bn + 1][bk] = f2bf(t4.y);
            Bs[bn + 2][bk] = f2bf(t4.z);
            Bs[bn + 3][bk] = f2bf(t4.w);
        }
        __syncthreads();
        short8 af[4], bfr[4];
#pragma unroll
        for (int mt = 0; mt < 4; mt++) af[mt] = *(short8*)&As[wr * 64 + mt * 16 + l16][quad * 8];
#pragma unroll
        for (int nt = 0; nt < 4; nt++) bfr[nt] = *(short8*)&Bs[wc * 64 + nt * 16 + l16][quad * 8];
#pragma unroll
        for (int mt = 0; mt < 4; mt++)
#pragma unroll
            for (int nt = 0; nt < 4; nt++) acc[mt][nt] = MFMA16(af[mt], bfr[nt], acc[mt][nt]);
    }

#pragma unroll
    for (int mt = 0; mt < 4; mt++)
#pragma unroll
        for (int nt = 0; nt < 4; nt++) {
            const int n = n0 + wc * 64 + nt * 16 + l16;
#pragma unroll
            for (int r = 0; r < 4; r++) {
                const int m = m0 + wr * 64 + mt * 16 + quad * 4 + r;
                out[(size_t)m * 1024 + n] = acc[mt][nt][r];
            }
        }
}

// ---------------------------------------------------------------------------
extern "C" void kernel_launch(void* const* d_in, const int* in_sizes, int n_in,
                              void* d_out, int out_size, void* d_ws, size_t ws_size,
                              hipStream_t stream) {
    const float* x  = (const float*)d_in[0];   // [2,2048,1024] f32
    const float* Wa = (const float*)d_in[1];   // [1024,3072]  f32
    const float* Wp = (const float*)d_in[2];   // [1024,1024]  f32
    float* out = (float*)d_out;                // [2,2048,1024] f32

    const size_t PB = (size_t)2048 * 1024;     // per-batch elements
    ushort* qb  = (ushort*)d_ws;               // 4 MB bf16 q  [H,T,HD]
    ushort* kb  = qb + PB;                     // 4 MB bf16 k  [H,T,HD]
    ushort* vtb = kb + PB;                     // 4 MB bf16 v^T[H,HD,T]
    ushort* yb  = vtb + PB;                    // 4 MB bf16 y  [T,C]

    for (int b = 0; b < 2; b++) {
        gemm1_qkv_k<<<dim3(24, 16), 256, 0, stream>>>(x + b * PB, Wa, qb, kb, vtb);
        rope_k<<<dim3(8192), 256, 0, stream>>>(qb, kb);
        attn_valu_k<<<dim3(512), 64, 0, stream>>>(qb, kb, vtb, yb);
        gemm2_proj_k<<<dim3(8, 16), 256, 0, stream>>>(yb, Wp, out + b * PB);
    }
}

// Round 6
// 1334.919 us; speedup vs baseline: 2.9618x; 2.9618x over previous
//
#include <hip/hip_runtime.h>

// ---------------------------------------------------------------------------
// qkv = x@W_attn; RoPE(q,k); flash-attn; y@W_proj
// B=2, T=2048, C=1024, H=16, HD=64.  I/O fp32; internal tensors bf16.
//
// BISECT ROUND 2: attention = MFMA QK^T + online softmax (round-4 code,
// lane-level re-verified) + *exact fp32 VALU PV* (replaces the P->LDS->A-frag
// ->MFMA-PV path, the prime suspect).  P / alpha / L handed from the MFMA
// lane-layout to (row,part) VALU threads through LDS.
// ---------------------------------------------------------------------------

typedef __attribute__((ext_vector_type(8))) short short8;   // 8 bf16 = 4 VGPRs
typedef __attribute__((ext_vector_type(4))) float floatx4;  // MFMA C/D frag

__device__ __forceinline__ ushort f2bf(float f) {
    unsigned x = __float_as_uint(f);
    x += 0x7fffu + ((x >> 16) & 1u);   // round-to-nearest-even
    return (ushort)(x >> 16);
}
__device__ __forceinline__ float bf2f(ushort u) {
    return __uint_as_float(((unsigned)u) << 16);
}

#define MFMA16(a, b, c) __builtin_amdgcn_mfma_f32_16x16x32_bf16((a), (b), (c), 0, 0, 0)

// ---------------------------------------------------------------------------
// GEMM1 (one batch): qkv = x_b[2048][1024](f32) @ W_attn[1024][3072](f32) ->
//   q: [H,T,HD]   k: [H,T,HD]   v^T: [H,HD,T]   (bf16)    [verified round 5]
// ---------------------------------------------------------------------------
__global__ __launch_bounds__(256, 2) void gemm1_qkv_k(const float* __restrict__ A,
                                                      const float* __restrict__ Bw,
                                                      ushort* __restrict__ qb,
                                                      ushort* __restrict__ kb,
                                                      ushort* __restrict__ vtb) {
    __shared__ __align__(16) ushort As[128][40];   // As[m][k]
    __shared__ __align__(16) ushort Bs[128][40];   // Bs[n][k]
    const int tid = threadIdx.x;
    const int m0 = blockIdx.y * 128, n0 = blockIdx.x * 128;
    const int w = tid >> 6, lane = tid & 63, quad = lane >> 4, l16 = lane & 15;
    const int wr = w >> 1, wc = w & 1;
    const int K = 1024, N = 3072;

    floatx4 acc[4][4];
#pragma unroll
    for (int mt = 0; mt < 4; mt++)
#pragma unroll
        for (int nt = 0; nt < 4; nt++) acc[mt][nt] = (floatx4){0.f, 0.f, 0.f, 0.f};

    for (int k0 = 0; k0 < K; k0 += 32) {
        __syncthreads();
#pragma unroll
        for (int j = 0; j < 4; j++) {
            int flat = (tid + j * 256) * 4;
            int r = flat >> 5, c = flat & 31;
            float4 t4 = *(const float4*)&A[(size_t)(m0 + r) * K + k0 + c];
            ushort4 u4 = make_ushort4(f2bf(t4.x), f2bf(t4.y), f2bf(t4.z), f2bf(t4.w));
            *(ushort4*)&As[r][c] = u4;
        }
#pragma unroll
        for (int j = 0; j < 4; j++) {
            int flat = (tid + j * 256) * 4;
            int bk = flat >> 7, bn = flat & 127;
            float4 t4 = *(const float4*)&Bw[(size_t)(k0 + bk) * N + n0 + bn];
            Bs[bn + 0][bk] = f2bf(t4.x);
            Bs[bn + 1][bk] = f2bf(t4.y);
            Bs[bn + 2][bk] = f2bf(t4.z);
            Bs[bn + 3][bk] = f2bf(t4.w);
        }
        __syncthreads();
        short8 af[4], bfr[4];
#pragma unroll
        for (int mt = 0; mt < 4; mt++) af[mt] = *(short8*)&As[wr * 64 + mt * 16 + l16][quad * 8];
#pragma unroll
        for (int nt = 0; nt < 4; nt++) bfr[nt] = *(short8*)&Bs[wc * 64 + nt * 16 + l16][quad * 8];
#pragma unroll
        for (int mt = 0; mt < 4; mt++)
#pragma unroll
            for (int nt = 0; nt < 4; nt++) acc[mt][nt] = MFMA16(af[mt], bfr[nt], acc[mt][nt]);
    }

#pragma unroll
    for (int nt = 0; nt < 4; nt++) {
        const int n = n0 + wc * 64 + nt * 16 + l16;
        const int seg = n >> 10;          // 0=q 1=k 2=v
        const int cn = n & 1023;
        const int h = cn >> 6, d = cn & 63;
#pragma unroll
        for (int mt = 0; mt < 4; mt++) {
#pragma unroll
            for (int r = 0; r < 4; r++) {
                const int t = m0 + wr * 64 + mt * 16 + quad * 4 + r;
                const ushort v = f2bf(acc[mt][nt][r]);
                if (seg == 0)      qb[((size_t)h * 2048 + t) * 64 + d] = v;
                else if (seg == 1) kb[((size_t)h * 2048 + t) * 64 + d] = v;
                else               vtb[((size_t)h * 64 + d) * 2048 + t] = v;
            }
        }
    }
}

// ---------------------------------------------------------------------------
// RoPE (roll variant), f64 trig  [verified round 5]
// ---------------------------------------------------------------------------
__global__ __launch_bounds__(256) void rope_k(ushort* __restrict__ q, ushort* __restrict__ k) {
    const int wid = blockIdx.x * 4 + (threadIdx.x >> 6);  // row = h*2048 + t
    const int lane = threadIdx.x & 63;
    const int t = wid & 2047;
    const int j = lane & 31;
    const double inv = pow(10000.0, -(double)j / 32.0);
    const double ang = (double)t * inv;
    const float c = (float)cos(ang);
    const float s = (float)sin(ang);
    const size_t base = (size_t)wid * 64;

    float qv = bf2f(q[base + lane]);
    float qp = __shfl(qv, (lane + 63) & 63, 64);
    q[base + lane] = f2bf(qv * c + qp * s);

    float kv = bf2f(k[base + lane]);
    float kp = __shfl(kv, (lane + 63) & 63, 64);
    k[base + lane] = f2bf(kv * c + kp * s);
}

// ---------------------------------------------------------------------------
// Hybrid flash attention (causal), one batch.  Block = (h, 64-row q-tile),
// 256 threads.  Phase 1 (MFMA lane layout): QK^T + online softmax -> fp32 P,
// alpha, L into LDS.  Phase 2 ((row,part) layout): exact VALU PV.
// ---------------------------------------------------------------------------
__global__ __launch_bounds__(256, 2) void attn_hyb_k(const ushort* __restrict__ q,
                                                     const ushort* __restrict__ k,
                                                     const ushort* __restrict__ vt,
                                                     ushort* __restrict__ y) {
    __shared__ __align__(16) ushort Ks[64][72];   // [key][d] bf16 (MFMA B-frags)
    __shared__ float Vs[64][65];                  // [d][key] fp32 (VALU PV)
    __shared__ float Ps[64][65];                  // [row][key] fp32 P
    __shared__ float alphaS[64];
    __shared__ float LS[64];

    const int qt = 31 - (blockIdx.x & 31);        // big tiles first
    const int h = blockIdx.x >> 5;
    const int tid = threadIdx.x, w = tid >> 6, lane = tid & 63;
    const int quad = lane >> 4, l16 = lane & 15;
    const int q0 = qt * 64;
    const int row = tid >> 2;                     // PV: q-row 0..63
    const int part = tid & 3;                     // PV: dims [part*16, +16)

    // MFMA-side Q fragments
    short8 qa0, qa1;
    {
        const int qrow = q0 + w * 16 + l16;
        const ushort* qp = q + ((size_t)h * 2048 + qrow) * 64 + quad * 8;
        qa0 = *(const short8*)(qp);
        qa1 = *(const short8*)(qp + 32);
    }

    float O[16];
#pragma unroll
    for (int dd = 0; dd < 16; dd++) O[dd] = 0.f;
    float M[4] = {-30000.f, -30000.f, -30000.f, -30000.f};
    float L[4] = {0.f, 0.f, 0.f, 0.f};

    for (int kt = 0; kt <= qt; kt++) {
        const int kbase = kt * 64;
        __syncthreads();   // (A) prior tile fully consumed
        // --- stage K (bf16) and V (fp32, [d][key]) ---
#pragma unroll
        for (int jj = 0; jj < 2; jj++) {
            int flat = (tid + jj * 256) * 8;
            int r = flat >> 6, c = flat & 63;
            *(uint4*)&Ks[r][c] = *(const uint4*)&k[((size_t)h * 2048 + kbase + r) * 64 + c];
            const ushort* vp = &vt[((size_t)h * 64 + r) * 2048 + kbase + c];
#pragma unroll
            for (int e = 0; e < 8; e++) Vs[r][c + e] = bf2f(vp[e]);
        }
        __syncthreads();   // (B) staging complete

        // --- Phase 1: S = Q K^T (MFMA), mask, online softmax ---
        floatx4 s[4];
#pragma unroll
        for (int nt = 0; nt < 4; nt++) {
            short8 kb0 = *(short8*)&Ks[nt * 16 + l16][quad * 8];
            short8 kb1 = *(short8*)&Ks[nt * 16 + l16][32 + quad * 8];
            floatx4 z = (floatx4){0.f, 0.f, 0.f, 0.f};
            z = MFMA16(qa0, kb0, z);
            z = MFMA16(qa1, kb1, z);
            s[nt] = z;
        }

        const bool diag = (kt == qt);
#pragma unroll
        for (int nt = 0; nt < 4; nt++) {
            const int kidx = kbase + nt * 16 + l16;
#pragma unroll
            for (int r = 0; r < 4; r++) {
                float v = s[nt][r] * 0.125f;   // 1/sqrt(64)
                if (diag) {
                    const int qi = q0 + w * 16 + quad * 4 + r;
                    if (kidx > qi) v = -30000.f;
                }
                s[nt][r] = v;
            }
        }

#pragma unroll
        for (int r = 0; r < 4; r++) {
            float mx = fmaxf(fmaxf(s[0][r], s[1][r]), fmaxf(s[2][r], s[3][r]));
            mx = fmaxf(mx, __shfl_xor(mx, 1, 64));
            mx = fmaxf(mx, __shfl_xor(mx, 2, 64));
            mx = fmaxf(mx, __shfl_xor(mx, 4, 64));
            mx = fmaxf(mx, __shfl_xor(mx, 8, 64));
            const float Mn = fmaxf(M[r], mx);
            const float alpha = __expf(M[r] - Mn);
            float sum = 0.f;
#pragma unroll
            for (int nt = 0; nt < 4; nt++) {
                float p = __expf(s[nt][r] - Mn);
                s[nt][r] = p;
                sum += p;
            }
            sum += __shfl_xor(sum, 1, 64);
            sum += __shfl_xor(sum, 2, 64);
            sum += __shfl_xor(sum, 4, 64);
            sum += __shfl_xor(sum, 8, 64);
            L[r] = L[r] * alpha + sum;
            M[r] = Mn;
            const int rW = w * 16 + quad * 4 + r;   // tile-row this lane owns
            alphaS[rW] = alpha;                     // 16 l16-lanes write same value
            LS[rW] = L[r];
#pragma unroll
            for (int nt = 0; nt < 4; nt++) Ps[rW][nt * 16 + l16] = s[nt][r];
        }
        __syncthreads();   // (C) P/alpha visible

        // --- Phase 2: exact VALU PV in (row,part) layout ---
        const float alpha = alphaS[row];
#pragma unroll
        for (int dd = 0; dd < 16; dd++) O[dd] *= alpha;
        for (int n = 0; n < 64; n++) {
            const float p = Ps[row][n];
#pragma unroll
            for (int dd = 0; dd < 16; dd++) O[dd] += p * Vs[part * 16 + dd][n];
        }
    }

    // Epilogue ((row,part) layout): y[t][h*64+d] row-major [2048][1024] bf16
    const float rl = 1.0f / LS[row];
    ushort* yp = y + (size_t)(q0 + row) * 1024 + h * 64 + part * 16;
#pragma unroll
    for (int dd = 0; dd < 16; dd++) yp[dd] = f2bf(O[dd] * rl);
}

// ---------------------------------------------------------------------------
// GEMM2 (one batch): out(f32) = y[2048][1024](bf16) @ W_proj[1024][1024](f32)
// [verified round 5]
// ---------------------------------------------------------------------------
__global__ __launch_bounds__(256, 2) void gemm2_proj_k(const ushort* __restrict__ Y,
                                                       const float* __restrict__ Bw,
                                                       float* __restrict__ out) {
    __shared__ __align__(16) ushort As[128][40];
    __shared__ __align__(16) ushort Bs[128][40];
    const int tid = threadIdx.x;
    const int m0 = blockIdx.y * 128, n0 = blockIdx.x * 128;
    const int w = tid >> 6, lane = tid & 63, quad = lane >> 4, l16 = lane & 15;
    const int wr = w >> 1, wc = w & 1;
    const int K = 1024, N = 1024;

    floatx4 acc[4][4];
#pragma unroll
    for (int mt = 0; mt < 4; mt++)
#pragma unroll
        for (int nt = 0; nt < 4; nt++) acc[mt][nt] = (floatx4){0.f, 0.f, 0.f, 0.f};

    for (int k0 = 0; k0 < K; k0 += 32) {
        __syncthreads();
#pragma unroll
        for (int j = 0; j < 2; j++) {
            int flat = (tid + j * 256) * 8;
            int r = flat >> 5, c = flat & 31;
            *(uint4*)&As[r][c] = *(const uint4*)&Y[(size_t)(m0 + r) * K + k0 + c];
        }
#pragma unroll
        for (int j = 0; j < 4; j++) {
            int flat = (tid + j * 256) * 4;
            int bk = flat >> 7, bn = flat & 127;
            float4 t4 = *(const float4*)&Bw[(size_t)(k0 + bk) * N + n0 + bn];
            Bs[bn + 0][bk] = f2bf(t4.x);
            Bs[bn + 1][bk] = f2bf(t4.y);
            Bs[bn + 2][bk] = f2bf(t4.z);
            Bs[bn + 3][bk] = f2bf(t4.w);
        }
        __syncthreads();
        short8 af[4], bfr[4];
#pragma unroll
        for (int mt = 0; mt < 4; mt++) af[mt] = *(short8*)&As[wr * 64 + mt * 16 + l16][quad * 8];
#pragma unroll
        for (int nt = 0; nt < 4; nt++) bfr[nt] = *(short8*)&Bs[wc * 64 + nt * 16 + l16][quad * 8];
#pragma unroll
        for (int mt = 0; mt < 4; mt++)
#pragma unroll
            for (int nt = 0; nt < 4; nt++) acc[mt][nt] = MFMA16(af[mt], bfr[nt], acc[mt][nt]);
    }

#pragma unroll
    for (int mt = 0; mt < 4; mt++)
#pragma unroll
        for (int nt = 0; nt < 4; nt++) {
            const int n = n0 + wc * 64 + nt * 16 + l16;
#pragma unroll
            for (int r = 0; r < 4; r++) {
                const int m = m0 + wr * 64 + mt * 16 + quad * 4 + r;
                out[(size_t)m * 1024 + n] = acc[mt][nt][r];
            }
        }
}

// ---------------------------------------------------------------------------
extern "C" void kernel_launch(void* const* d_in, const int* in_sizes, int n_in,
                              void* d_out, int out_size, void* d_ws, size_t ws_size,
                              hipStream_t stream) {
    const float* x  = (const float*)d_in[0];   // [2,2048,1024] f32
    const float* Wa = (const float*)d_in[1];   // [1024,3072]  f32
    const float* Wp = (const float*)d_in[2];   // [1024,1024]  f32
    float* out = (float*)d_out;                // [2,2048,1024] f32

    const size_t PB = (size_t)2048 * 1024;     // per-batch elements
    ushort* qb  = (ushort*)d_ws;               // 4 MB bf16 q  [H,T,HD]
    ushort* kb  = qb + PB;                     // 4 MB bf16 k  [H,T,HD]
    ushort* vtb = kb + PB;                     // 4 MB bf16 v^T[H,HD,T]
    ushort* yb  = vtb + PB;                    // 4 MB bf16 y  [T,C]

    for (int b = 0; b < 2; b++) {
        gemm1_qkv_k<<<dim3(24, 16), 256, 0, stream>>>(x + b * PB, Wa, qb, kb, vtb);
        rope_k<<<dim3(8192), 256, 0, stream>>>(qb, kb);
        attn_hyb_k<<<dim3(512), 256, 0, stream>>>(qb, kb, vtb, yb);
        gemm2_proj_k<<<dim3(8, 16), 256, 0, stream>>>(yb, Wp, out + b * PB);
    }
}

// Round 7
// 813.385 us; speedup vs baseline: 4.8608x; 1.6412x over previous
//
#include <hip/hip_runtime.h>

// ---------------------------------------------------------------------------
// qkv = x@W_attn; RoPE(q,k); flash-attn; y@W_proj
// B=2, T=2048, C=1024, H=16, HD=64.  I/O fp32; internal tensors bf16.
//
// Attention: MFMA QK^T + online softmax (HW-verified R6) + VALU PV, now
// vectorized to b128 LDS reads (V stored [key][d] fp32, P rows 16B-aligned).
// The R4 MFMA-PV path stays quarantined (unexplained fail) — next experiment.
// ---------------------------------------------------------------------------

typedef __attribute__((ext_vector_type(8))) short short8;   // 8 bf16 = 4 VGPRs
typedef __attribute__((ext_vector_type(4))) float floatx4;  // MFMA C/D frag

__device__ __forceinline__ ushort f2bf(float f) {
    unsigned x = __float_as_uint(f);
    x += 0x7fffu + ((x >> 16) & 1u);   // round-to-nearest-even
    return (ushort)(x >> 16);
}
__device__ __forceinline__ float bf2f(ushort u) {
    return __uint_as_float(((unsigned)u) << 16);
}

#define MFMA16(a, b, c) __builtin_amdgcn_mfma_f32_16x16x32_bf16((a), (b), (c), 0, 0, 0)

// ---------------------------------------------------------------------------
// GEMM1 (one batch): qkv = x_b[2048][1024](f32) @ W_attn[1024][3072](f32) ->
//   q,k,v: [H,T,HD] bf16  (v now un-transposed — attn stages [key][d] direct)
// ---------------------------------------------------------------------------
__global__ __launch_bounds__(256, 2) void gemm1_qkv_k(const float* __restrict__ A,
                                                      const float* __restrict__ Bw,
                                                      ushort* __restrict__ qb,
                                                      ushort* __restrict__ kb,
                                                      ushort* __restrict__ vb) {
    __shared__ __align__(16) ushort As[128][40];   // As[m][k]
    __shared__ __align__(16) ushort Bs[128][40];   // Bs[n][k]
    const int tid = threadIdx.x;
    const int m0 = blockIdx.y * 128, n0 = blockIdx.x * 128;
    const int w = tid >> 6, lane = tid & 63, quad = lane >> 4, l16 = lane & 15;
    const int wr = w >> 1, wc = w & 1;
    const int K = 1024, N = 3072;

    floatx4 acc[4][4];
#pragma unroll
    for (int mt = 0; mt < 4; mt++)
#pragma unroll
        for (int nt = 0; nt < 4; nt++) acc[mt][nt] = (floatx4){0.f, 0.f, 0.f, 0.f};

    for (int k0 = 0; k0 < K; k0 += 32) {
        __syncthreads();
#pragma unroll
        for (int j = 0; j < 4; j++) {
            int flat = (tid + j * 256) * 4;
            int r = flat >> 5, c = flat & 31;
            float4 t4 = *(const float4*)&A[(size_t)(m0 + r) * K + k0 + c];
            ushort4 u4 = make_ushort4(f2bf(t4.x), f2bf(t4.y), f2bf(t4.z), f2bf(t4.w));
            *(ushort4*)&As[r][c] = u4;
        }
#pragma unroll
        for (int j = 0; j < 4; j++) {
            int flat = (tid + j * 256) * 4;
            int bk = flat >> 7, bn = flat & 127;
            float4 t4 = *(const float4*)&Bw[(size_t)(k0 + bk) * N + n0 + bn];
            Bs[bn + 0][bk] = f2bf(t4.x);
            Bs[bn + 1][bk] = f2bf(t4.y);
            Bs[bn + 2][bk] = f2bf(t4.z);
            Bs[bn + 3][bk] = f2bf(t4.w);
        }
        __syncthreads();
        short8 af[4], bfr[4];
#pragma unroll
        for (int mt = 0; mt < 4; mt++) af[mt] = *(short8*)&As[wr * 64 + mt * 16 + l16][quad * 8];
#pragma unroll
        for (int nt = 0; nt < 4; nt++) bfr[nt] = *(short8*)&Bs[wc * 64 + nt * 16 + l16][quad * 8];
#pragma unroll
        for (int mt = 0; mt < 4; mt++)
#pragma unroll
            for (int nt = 0; nt < 4; nt++) acc[mt][nt] = MFMA16(af[mt], bfr[nt], acc[mt][nt]);
    }

#pragma unroll
    for (int nt = 0; nt < 4; nt++) {
        const int n = n0 + wc * 64 + nt * 16 + l16;
        const int seg = n >> 10;          // 0=q 1=k 2=v
        const int cn = n & 1023;
        const int h = cn >> 6, d = cn & 63;
#pragma unroll
        for (int mt = 0; mt < 4; mt++) {
#pragma unroll
            for (int r = 0; r < 4; r++) {
                const int t = m0 + wr * 64 + mt * 16 + quad * 4 + r;
                const ushort v = f2bf(acc[mt][nt][r]);
                if (seg == 0)      qb[((size_t)h * 2048 + t) * 64 + d] = v;
                else if (seg == 1) kb[((size_t)h * 2048 + t) * 64 + d] = v;
                else               vb[((size_t)h * 2048 + t) * 64 + d] = v;
            }
        }
    }
}

// ---------------------------------------------------------------------------
// RoPE (roll variant), f64 trig  [verified R5/R6]
// ---------------------------------------------------------------------------
__global__ __launch_bounds__(256) void rope_k(ushort* __restrict__ q, ushort* __restrict__ k) {
    const int wid = blockIdx.x * 4 + (threadIdx.x >> 6);  // row = h*2048 + t
    const int lane = threadIdx.x & 63;
    const int t = wid & 2047;
    const int j = lane & 31;
    const double inv = pow(10000.0, -(double)j / 32.0);
    const double ang = (double)t * inv;
    const float c = (float)cos(ang);
    const float s = (float)sin(ang);
    const size_t base = (size_t)wid * 64;

    float qv = bf2f(q[base + lane]);
    float qp = __shfl(qv, (lane + 63) & 63, 64);
    q[base + lane] = f2bf(qv * c + qp * s);

    float kv = bf2f(k[base + lane]);
    float kp = __shfl(kv, (lane + 63) & 63, 64);
    k[base + lane] = f2bf(kv * c + kp * s);
}

// ---------------------------------------------------------------------------
// Hybrid flash attention (causal), one batch.  Block = (h, 64-row q-tile),
// 256 threads.  Phase 1 (MFMA lane layout): QK^T + online softmax -> fp32 P,
// alpha, L in LDS.  Phase 2 ((row,part) layout): VALU PV with b128 reads.
// ---------------------------------------------------------------------------
__global__ __launch_bounds__(256, 2) void attn_hyb_k(const ushort* __restrict__ q,
                                                     const ushort* __restrict__ k,
                                                     const ushort* __restrict__ v,
                                                     ushort* __restrict__ y) {
    __shared__ __align__(16) ushort Ks[64][72];   // [key][d] bf16 (MFMA B-frags)
    __shared__ __align__(16) float Vs[64][68];    // [key][d] fp32 (16B-aligned rows)
    __shared__ __align__(16) float Ps[64][68];    // [row][key] fp32 P
    __shared__ float alphaS[64];
    __shared__ float LS[64];

    const int qt = 31 - (blockIdx.x & 31);        // big tiles first
    const int h = blockIdx.x >> 5;
    const int tid = threadIdx.x, w = tid >> 6, lane = tid & 63;
    const int quad = lane >> 4, l16 = lane & 15;
    const int q0 = qt * 64;
    const int row = tid >> 2;                     // PV: q-row 0..63
    const int part = tid & 3;                     // PV: dims [part*16, +16)

    // MFMA-side Q fragments
    short8 qa0, qa1;
    {
        const int qrow = q0 + w * 16 + l16;
        const ushort* qp = q + ((size_t)h * 2048 + qrow) * 64 + quad * 8;
        qa0 = *(const short8*)(qp);
        qa1 = *(const short8*)(qp + 32);
    }

    floatx4 O[4];
#pragma unroll
    for (int dd = 0; dd < 4; dd++) O[dd] = (floatx4){0.f, 0.f, 0.f, 0.f};
    float M[4] = {-30000.f, -30000.f, -30000.f, -30000.f};
    float L[4] = {0.f, 0.f, 0.f, 0.f};

    for (int kt = 0; kt <= qt; kt++) {
        const int kbase = kt * 64;
        __syncthreads();   // (A) prior tile fully consumed
        // --- stage K (bf16 [key][d]) and V (fp32 [key][d]) ---
#pragma unroll
        for (int jj = 0; jj < 2; jj++) {
            int flat = (tid + jj * 256) * 8;
            int r = flat >> 6, c = flat & 63;
            uint4 kt4 = *(const uint4*)&k[((size_t)h * 2048 + kbase + r) * 64 + c];
            *(uint4*)&Ks[r][c] = kt4;
            uint4 vt4 = *(const uint4*)&v[((size_t)h * 2048 + kbase + r) * 64 + c];
            const ushort* vp = (const ushort*)&vt4;
            floatx4 f0 = {bf2f(vp[0]), bf2f(vp[1]), bf2f(vp[2]), bf2f(vp[3])};
            floatx4 f1 = {bf2f(vp[4]), bf2f(vp[5]), bf2f(vp[6]), bf2f(vp[7])};
            *(floatx4*)&Vs[r][c] = f0;
            *(floatx4*)&Vs[r][c + 4] = f1;
        }
        __syncthreads();   // (B) staging complete

        // --- Phase 1: S = Q K^T (MFMA), mask, online softmax ---
        floatx4 s[4];
#pragma unroll
        for (int nt = 0; nt < 4; nt++) {
            short8 kb0 = *(short8*)&Ks[nt * 16 + l16][quad * 8];
            short8 kb1 = *(short8*)&Ks[nt * 16 + l16][32 + quad * 8];
            floatx4 z = (floatx4){0.f, 0.f, 0.f, 0.f};
            z = MFMA16(qa0, kb0, z);
            z = MFMA16(qa1, kb1, z);
            s[nt] = z;
        }

        const bool diag = (kt == qt);
#pragma unroll
        for (int nt = 0; nt < 4; nt++) {
            const int kidx = kbase + nt * 16 + l16;
#pragma unroll
            for (int r = 0; r < 4; r++) {
                float vv = s[nt][r] * 0.125f;   // 1/sqrt(64)
                if (diag) {
                    const int qi = q0 + w * 16 + quad * 4 + r;
                    if (kidx > qi) vv = -30000.f;
                }
                s[nt][r] = vv;
            }
        }

#pragma unroll
        for (int r = 0; r < 4; r++) {
            float mx = fmaxf(fmaxf(s[0][r], s[1][r]), fmaxf(s[2][r], s[3][r]));
            mx = fmaxf(mx, __shfl_xor(mx, 1, 64));
            mx = fmaxf(mx, __shfl_xor(mx, 2, 64));
            mx = fmaxf(mx, __shfl_xor(mx, 4, 64));
            mx = fmaxf(mx, __shfl_xor(mx, 8, 64));
            const float Mn = fmaxf(M[r], mx);
            const float alpha = __expf(M[r] - Mn);
            float sum = 0.f;
#pragma unroll
            for (int nt = 0; nt < 4; nt++) {
                float p = __expf(s[nt][r] - Mn);
                s[nt][r] = p;
                sum += p;
            }
            sum += __shfl_xor(sum, 1, 64);
            sum += __shfl_xor(sum, 2, 64);
            sum += __shfl_xor(sum, 4, 64);
            sum += __shfl_xor(sum, 8, 64);
            L[r] = L[r] * alpha + sum;
            M[r] = Mn;
            const int rW = w * 16 + quad * 4 + r;   // tile-row this lane owns
            alphaS[rW] = alpha;                     // 16 l16-lanes write same value
            LS[rW] = L[r];
#pragma unroll
            for (int nt = 0; nt < 4; nt++) Ps[rW][nt * 16 + l16] = s[nt][r];
        }
        __syncthreads();   // (C) P/alpha visible

        // --- Phase 2: VALU PV in (row,part) layout, b128 reads ---
        const float alpha = alphaS[row];
#pragma unroll
        for (int dd = 0; dd < 4; dd++) O[dd] *= alpha;
        for (int n4 = 0; n4 < 64; n4 += 4) {
            floatx4 p4 = *(floatx4*)&Ps[row][n4];
#pragma unroll
            for (int e = 0; e < 4; e++) {
                const float p = p4[e];
                const float* vr = &Vs[n4 + e][part * 16];
                floatx4 v0 = *(const floatx4*)(vr);
                floatx4 v1 = *(const floatx4*)(vr + 4);
                floatx4 v2 = *(const floatx4*)(vr + 8);
                floatx4 v3 = *(const floatx4*)(vr + 12);
                O[0] += p * v0;
                O[1] += p * v1;
                O[2] += p * v2;
                O[3] += p * v3;
            }
        }
    }

    // Epilogue ((row,part) layout): y[t][h*64+d] row-major [2048][1024] bf16
    const float rl = 1.0f / LS[row];
    ushort* yp = y + (size_t)(q0 + row) * 1024 + h * 64 + part * 16;
#pragma unroll
    for (int dd = 0; dd < 4; dd++)
#pragma unroll
        for (int e = 0; e < 4; e++) yp[dd * 4 + e] = f2bf(O[dd][e] * rl);
}

// ---------------------------------------------------------------------------
// GEMM2 (one batch): out(f32) = y[2048][1024](bf16) @ W_proj[1024][1024](f32)
// [verified R5/R6]
// ---------------------------------------------------------------------------
__global__ __launch_bounds__(256, 2) void gemm2_proj_k(const ushort* __restrict__ Y,
                                                       const float* __restrict__ Bw,
                                                       float* __restrict__ out) {
    __shared__ __align__(16) ushort As[128][40];
    __shared__ __align__(16) ushort Bs[128][40];
    const int tid = threadIdx.x;
    const int m0 = blockIdx.y * 128, n0 = blockIdx.x * 128;
    const int w = tid >> 6, lane = tid & 63, quad = lane >> 4, l16 = lane & 15;
    const int wr = w >> 1, wc = w & 1;
    const int K = 1024, N = 1024;

    floatx4 acc[4][4];
#pragma unroll
    for (int mt = 0; mt < 4; mt++)
#pragma unroll
        for (int nt = 0; nt < 4; nt++) acc[mt][nt] = (floatx4){0.f, 0.f, 0.f, 0.f};

    for (int k0 = 0; k0 < K; k0 += 32) {
        __syncthreads();
#pragma unroll
        for (int j = 0; j < 2; j++) {
            int flat = (tid + j * 256) * 8;
            int r = flat >> 5, c = flat & 31;
            *(uint4*)&As[r][c] = *(const uint4*)&Y[(size_t)(m0 + r) * K + k0 + c];
        }
#pragma unroll
        for (int j = 0; j < 4; j++) {
            int flat = (tid + j * 256) * 4;
            int bk = flat >> 7, bn = flat & 127;
            float4 t4 = *(const float4*)&Bw[(size_t)(k0 + bk) * N + n0 + bn];
            Bs[bn + 0][bk] = f2bf(t4.x);
            Bs[bn + 1][bk] = f2bf(t4.y);
            Bs[bn + 2][bk] = f2bf(t4.z);
            Bs[bn + 3][bk] = f2bf(t4.w);
        }
        __syncthreads();
        short8 af[4], bfr[4];
#pragma unroll
        for (int mt = 0; mt < 4; mt++) af[mt] = *(short8*)&As[wr * 64 + mt * 16 + l16][quad * 8];
#pragma unroll
        for (int nt = 0; nt < 4; nt++) bfr[nt] = *(short8*)&Bs[wc * 64 + nt * 16 + l16][quad * 8];
#pragma unroll
        for (int mt = 0; mt < 4; mt++)
#pragma unroll
            for (int nt = 0; nt < 4; nt++) acc[mt][nt] = MFMA16(af[mt], bfr[nt], acc[mt][nt]);
    }

#pragma unroll
    for (int mt = 0; mt < 4; mt++)
#pragma unroll
        for (int nt = 0; nt < 4; nt++) {
            const int n = n0 + wc * 64 + nt * 16 + l16;
#pragma unroll
            for (int r = 0; r < 4; r++) {
                const int m = m0 + wr * 64 + mt * 16 + quad * 4 + r;
                out[(size_t)m * 1024 + n] = acc[mt][nt][r];
            }
        }
}

// ---------------------------------------------------------------------------
extern "C" void kernel_launch(void* const* d_in, const int* in_sizes, int n_in,
                              void* d_out, int out_size, void* d_ws, size_t ws_size,
                              hipStream_t stream) {
    const float* x  = (const float*)d_in[0];   // [2,2048,1024] f32
    const float* Wa = (const float*)d_in[1];   // [1024,3072]  f32
    const float* Wp = (const float*)d_in[2];   // [1024,1024]  f32
    float* out = (float*)d_out;                // [2,2048,1024] f32

    const size_t PB = (size_t)2048 * 1024;     // per-batch elements
    ushort* qb = (ushort*)d_ws;                // 4 MB bf16 q [H,T,HD]
    ushort* kb = qb + PB;                      // 4 MB bf16 k [H,T,HD]
    ushort* vb = kb + PB;                      // 4 MB bf16 v [H,T,HD]
    ushort* yb = vb + PB;                      // 4 MB bf16 y [T,C]

    for (int b = 0; b < 2; b++) {
        gemm1_qkv_k<<<dim3(24, 16), 256, 0, stream>>>(x + b * PB, Wa, qb, kb, vb);
        rope_k<<<dim3(8192), 256, 0, stream>>>(qb, kb);
        attn_hyb_k<<<dim3(512), 256, 0, stream>>>(qb, kb, vb, yb);
        gemm2_proj_k<<<dim3(8, 16), 256, 0, stream>>>(yb, Wp, out + b * PB);
    }
}

// Round 8
// 613.511 us; speedup vs baseline: 6.4444x; 1.3258x over previous
//
#include <hip/hip_runtime.h>

// ---------------------------------------------------------------------------
// qkv = x@W_attn; RoPE(q,k); flash-attn; y@W_proj
// B=2, T=2048, C=1024, H=16, HD=64.  I/O fp32; internal tensors bf16.
//
// EXPERIMENT: reintroduce MFMA PV (the R4-quarantined 10-line segment) on the
// otherwise fully HW-verified R7 scaffold.  Single variable: P->bf16 LDS
// (A-layout) -> MFMA PV with Vs bf16 [d][key], O in C-layout registers.
// ---------------------------------------------------------------------------

typedef __attribute__((ext_vector_type(8))) short short8;   // 8 bf16 = 4 VGPRs
typedef __attribute__((ext_vector_type(4))) float floatx4;  // MFMA C/D frag

__device__ __forceinline__ ushort f2bf(float f) {
    unsigned x = __float_as_uint(f);
    x += 0x7fffu + ((x >> 16) & 1u);   // round-to-nearest-even
    return (ushort)(x >> 16);
}
__device__ __forceinline__ float bf2f(ushort u) {
    return __uint_as_float(((unsigned)u) << 16);
}

#define MFMA16(a, b, c) __builtin_amdgcn_mfma_f32_16x16x32_bf16((a), (b), (c), 0, 0, 0)

// ---------------------------------------------------------------------------
// GEMM1 (one batch): qkv = x_b[2048][1024](f32) @ W_attn[1024][3072](f32) ->
//   q: [H,T,HD]   k: [H,T,HD]   v^T: [H,HD,T]   (bf16)   [verified R5/R6]
// ---------------------------------------------------------------------------
__global__ __launch_bounds__(256, 2) void gemm1_qkv_k(const float* __restrict__ A,
                                                      const float* __restrict__ Bw,
                                                      ushort* __restrict__ qb,
                                                      ushort* __restrict__ kb,
                                                      ushort* __restrict__ vtb) {
    __shared__ __align__(16) ushort As[128][40];   // As[m][k]
    __shared__ __align__(16) ushort Bs[128][40];   // Bs[n][k]
    const int tid = threadIdx.x;
    const int m0 = blockIdx.y * 128, n0 = blockIdx.x * 128;
    const int w = tid >> 6, lane = tid & 63, quad = lane >> 4, l16 = lane & 15;
    const int wr = w >> 1, wc = w & 1;
    const int K = 1024, N = 3072;

    floatx4 acc[4][4];
#pragma unroll
    for (int mt = 0; mt < 4; mt++)
#pragma unroll
        for (int nt = 0; nt < 4; nt++) acc[mt][nt] = (floatx4){0.f, 0.f, 0.f, 0.f};

    for (int k0 = 0; k0 < K; k0 += 32) {
        __syncthreads();
#pragma unroll
        for (int j = 0; j < 4; j++) {
            int flat = (tid + j * 256) * 4;
            int r = flat >> 5, c = flat & 31;
            float4 t4 = *(const float4*)&A[(size_t)(m0 + r) * K + k0 + c];
            ushort4 u4 = make_ushort4(f2bf(t4.x), f2bf(t4.y), f2bf(t4.z), f2bf(t4.w));
            *(ushort4*)&As[r][c] = u4;
        }
#pragma unroll
        for (int j = 0; j < 4; j++) {
            int flat = (tid + j * 256) * 4;
            int bk = flat >> 7, bn = flat & 127;
            float4 t4 = *(const float4*)&Bw[(size_t)(k0 + bk) * N + n0 + bn];
            Bs[bn + 0][bk] = f2bf(t4.x);
            Bs[bn + 1][bk] = f2bf(t4.y);
            Bs[bn + 2][bk] = f2bf(t4.z);
            Bs[bn + 3][bk] = f2bf(t4.w);
        }
        __syncthreads();
        short8 af[4], bfr[4];
#pragma unroll
        for (int mt = 0; mt < 4; mt++) af[mt] = *(short8*)&As[wr * 64 + mt * 16 + l16][quad * 8];
#pragma unroll
        for (int nt = 0; nt < 4; nt++) bfr[nt] = *(short8*)&Bs[wc * 64 + nt * 16 + l16][quad * 8];
#pragma unroll
        for (int mt = 0; mt < 4; mt++)
#pragma unroll
            for (int nt = 0; nt < 4; nt++) acc[mt][nt] = MFMA16(af[mt], bfr[nt], acc[mt][nt]);
    }

#pragma unroll
    for (int nt = 0; nt < 4; nt++) {
        const int n = n0 + wc * 64 + nt * 16 + l16;
        const int seg = n >> 10;          // 0=q 1=k 2=v
        const int cn = n & 1023;
        const int h = cn >> 6, d = cn & 63;
#pragma unroll
        for (int mt = 0; mt < 4; mt++) {
#pragma unroll
            for (int r = 0; r < 4; r++) {
                const int t = m0 + wr * 64 + mt * 16 + quad * 4 + r;
                const ushort v = f2bf(acc[mt][nt][r]);
                if (seg == 0)      qb[((size_t)h * 2048 + t) * 64 + d] = v;
                else if (seg == 1) kb[((size_t)h * 2048 + t) * 64 + d] = v;
                else               vtb[((size_t)h * 64 + d) * 2048 + t] = v;
            }
        }
    }
}

// ---------------------------------------------------------------------------
// RoPE (roll variant), f64 trig  [verified R5-R7]
// ---------------------------------------------------------------------------
__global__ __launch_bounds__(256) void rope_k(ushort* __restrict__ q, ushort* __restrict__ k) {
    const int wid = blockIdx.x * 4 + (threadIdx.x >> 6);  // row = h*2048 + t
    const int lane = threadIdx.x & 63;
    const int t = wid & 2047;
    const int j = lane & 31;
    const double inv = pow(10000.0, -(double)j / 32.0);
    const double ang = (double)t * inv;
    const float c = (float)cos(ang);
    const float s = (float)sin(ang);
    const size_t base = (size_t)wid * 64;

    float qv = bf2f(q[base + lane]);
    float qp = __shfl(qv, (lane + 63) & 63, 64);
    q[base + lane] = f2bf(qv * c + qp * s);

    float kv = bf2f(k[base + lane]);
    float kp = __shfl(kv, (lane + 63) & 63, 64);
    k[base + lane] = f2bf(kv * c + kp * s);
}

// ---------------------------------------------------------------------------
// Flash attention (causal), one batch.  Block = (h, 64-row q-tile), 4 waves,
// 16 q-rows/wave.  QK^T MFMA + online softmax (HW-verified R6/R7) +
// MFMA PV via P->bf16 LDS A-layout (the segment under test).
// ---------------------------------------------------------------------------
__global__ __launch_bounds__(256, 2) void attn_k(const ushort* __restrict__ q,
                                                 const ushort* __restrict__ k,
                                                 const ushort* __restrict__ vt,
                                                 ushort* __restrict__ y) {
    __shared__ __align__(16) ushort Ks[64][72];   // [key][d]  bf16
    __shared__ __align__(16) ushort Vs[64][72];   // [d][key]  bf16 (V^T)
    __shared__ __align__(16) ushort Ps[4][16][72];// per-wave P [row][key] bf16

    const int qt = 31 - (blockIdx.x & 31);        // big tiles first
    const int h = blockIdx.x >> 5;
    const int tid = threadIdx.x, w = tid >> 6, lane = tid & 63;
    const int quad = lane >> 4, l16 = lane & 15;
    const int q0 = qt * 64;

    short8 qa0, qa1;
    {
        const int qrow = q0 + w * 16 + l16;
        const ushort* qp = q + ((size_t)h * 2048 + qrow) * 64 + quad * 8;
        qa0 = *(const short8*)(qp);
        qa1 = *(const short8*)(qp + 32);
    }

    floatx4 O[4];
#pragma unroll
    for (int dt = 0; dt < 4; dt++) O[dt] = (floatx4){0.f, 0.f, 0.f, 0.f};
    float M[4] = {-30000.f, -30000.f, -30000.f, -30000.f};
    float L[4] = {0.f, 0.f, 0.f, 0.f};

    for (int kt = 0; kt <= qt; kt++) {
        const int kbase = kt * 64;
        __syncthreads();   // (A) prior tile fully consumed
#pragma unroll
        for (int jj = 0; jj < 2; jj++) {
            int flat = (tid + jj * 256) * 8;
            int r = flat >> 6, c = flat & 63;
            *(uint4*)&Ks[r][c] = *(const uint4*)&k[((size_t)h * 2048 + kbase + r) * 64 + c];
            *(uint4*)&Vs[r][c] = *(const uint4*)&vt[((size_t)h * 64 + r) * 2048 + kbase + c];
        }
        __syncthreads();   // (B) staging complete

        // --- QK^T (MFMA) + mask + online softmax  [verified R6/R7] ---
        floatx4 s[4];
#pragma unroll
        for (int nt = 0; nt < 4; nt++) {
            short8 kb0 = *(short8*)&Ks[nt * 16 + l16][quad * 8];
            short8 kb1 = *(short8*)&Ks[nt * 16 + l16][32 + quad * 8];
            floatx4 z = (floatx4){0.f, 0.f, 0.f, 0.f};
            z = MFMA16(qa0, kb0, z);
            z = MFMA16(qa1, kb1, z);
            s[nt] = z;
        }

        const bool diag = (kt == qt);
#pragma unroll
        for (int nt = 0; nt < 4; nt++) {
            const int kidx = kbase + nt * 16 + l16;
#pragma unroll
            for (int r = 0; r < 4; r++) {
                float vv = s[nt][r] * 0.125f;   // 1/sqrt(64)
                if (diag) {
                    const int qi = q0 + w * 16 + quad * 4 + r;
                    if (kidx > qi) vv = -30000.f;
                }
                s[nt][r] = vv;
            }
        }

#pragma unroll
        for (int r = 0; r < 4; r++) {
            float mx = fmaxf(fmaxf(s[0][r], s[1][r]), fmaxf(s[2][r], s[3][r]));
            mx = fmaxf(mx, __shfl_xor(mx, 1, 64));
            mx = fmaxf(mx, __shfl_xor(mx, 2, 64));
            mx = fmaxf(mx, __shfl_xor(mx, 4, 64));
            mx = fmaxf(mx, __shfl_xor(mx, 8, 64));
            const float Mn = fmaxf(M[r], mx);
            const float alpha = __expf(M[r] - Mn);
            float sum = 0.f;
#pragma unroll
            for (int nt = 0; nt < 4; nt++) {
                float p = __expf(s[nt][r] - Mn);
                s[nt][r] = p;
                sum += p;
            }
            sum += __shfl_xor(sum, 1, 64);
            sum += __shfl_xor(sum, 2, 64);
            sum += __shfl_xor(sum, 4, 64);
            sum += __shfl_xor(sum, 8, 64);
            L[r] = L[r] * alpha + sum;
            M[r] = Mn;
#pragma unroll
            for (int dt = 0; dt < 4; dt++) O[dt][r] *= alpha;
        }

        // --- SEGMENT UNDER TEST: P (C-layout) -> bf16 LDS -> A-frag -> PV ---
#pragma unroll
        for (int nt = 0; nt < 4; nt++)
#pragma unroll
            for (int r = 0; r < 4; r++)
                Ps[w][quad * 4 + r][nt * 16 + l16] = f2bf(s[nt][r]);
        __syncthreads();   // (C) P visible

        short8 pa0 = *(short8*)&Ps[w][l16][quad * 8];
        short8 pa1 = *(short8*)&Ps[w][l16][32 + quad * 8];
#pragma unroll
        for (int dt = 0; dt < 4; dt++) {
            short8 vb0 = *(short8*)&Vs[dt * 16 + l16][quad * 8];
            short8 vb1 = *(short8*)&Vs[dt * 16 + l16][32 + quad * 8];
            O[dt] = MFMA16(pa0, vb0, O[dt]);
            O[dt] = MFMA16(pa1, vb1, O[dt]);
        }
    }

    // Epilogue (C-layout): y[t][h*64+d], row-major [2048][1024] bf16
#pragma unroll
    for (int dt = 0; dt < 4; dt++)
#pragma unroll
        for (int r = 0; r < 4; r++) {
            const int t = q0 + w * 16 + quad * 4 + r;
            const float val = O[dt][r] / L[r];
            y[((size_t)t) * 1024 + h * 64 + dt * 16 + l16] = f2bf(val);
        }
}

// ---------------------------------------------------------------------------
// GEMM2 (one batch): out(f32) = y[2048][1024](bf16) @ W_proj[1024][1024](f32)
// [verified R5-R7]
// ---------------------------------------------------------------------------
__global__ __launch_bounds__(256, 2) void gemm2_proj_k(const ushort* __restrict__ Y,
                                                       const float* __restrict__ Bw,
                                                       float* __restrict__ out) {
    __shared__ __align__(16) ushort As[128][40];
    __shared__ __align__(16) ushort Bs[128][40];
    const int tid = threadIdx.x;
    const int m0 = blockIdx.y * 128, n0 = blockIdx.x * 128;
    const int w = tid >> 6, lane = tid & 63, quad = lane >> 4, l16 = lane & 15;
    const int wr = w >> 1, wc = w & 1;
    const int K = 1024, N = 1024;

    floatx4 acc[4][4];
#pragma unroll
    for (int mt = 0; mt < 4; mt++)
#pragma unroll
        for (int nt = 0; nt < 4; nt++) acc[mt][nt] = (floatx4){0.f, 0.f, 0.f, 0.f};

    for (int k0 = 0; k0 < K; k0 += 32) {
        __syncthreads();
#pragma unroll
        for (int j = 0; j < 2; j++) {
            int flat = (tid + j * 256) * 8;
            int r = flat >> 5, c = flat & 31;
            *(uint4*)&As[r][c] = *(const uint4*)&Y[(size_t)(m0 + r) * K + k0 + c];
        }
#pragma unroll
        for (int j = 0; j < 4; j++) {
            int flat = (tid + j * 256) * 4;
            int bk = flat >> 7, bn = flat & 127;
            float4 t4 = *(const float4*)&Bw[(size_t)(k0 + bk) * N + n0 + bn];
            Bs[bn + 0][bk] = f2bf(t4.x);
            Bs[bn + 1][bk] = f2bf(t4.y);
            Bs[bn + 2][bk] = f2bf(t4.z);
            Bs[bn + 3][bk] = f2bf(t4.w);
        }
        __syncthreads();
        short8 af[4], bfr[4];
#pragma unroll
        for (int mt = 0; mt < 4; mt++) af[mt] = *(short8*)&As[wr * 64 + mt * 16 + l16][quad * 8];
#pragma unroll
        for (int nt = 0; nt < 4; nt++) bfr[nt] = *(short8*)&Bs[wc * 64 + nt * 16 + l16][quad * 8];
#pragma unroll
        for (int mt = 0; mt < 4; mt++)
#pragma unroll
            for (int nt = 0; nt < 4; nt++) acc[mt][nt] = MFMA16(af[mt], bfr[nt], acc[mt][nt]);
    }

#pragma unroll
    for (int mt = 0; mt < 4; mt++)
#pragma unroll
        for (int nt = 0; nt < 4; nt++) {
            const int n = n0 + wc * 64 + nt * 16 + l16;
#pragma unroll
            for (int r = 0; r < 4; r++) {
                const int m = m0 + wr * 64 + mt * 16 + quad * 4 + r;
                out[(size_t)m * 1024 + n] = acc[mt][nt][r];
            }
        }
}

// ---------------------------------------------------------------------------
extern "C" void kernel_launch(void* const* d_in, const int* in_sizes, int n_in,
                              void* d_out, int out_size, void* d_ws, size_t ws_size,
                              hipStream_t stream) {
    const float* x  = (const float*)d_in[0];   // [2,2048,1024] f32
    const float* Wa = (const float*)d_in[1];   // [1024,3072]  f32
    const float* Wp = (const float*)d_in[2];   // [1024,1024]  f32
    float* out = (float*)d_out;                // [2,2048,1024] f32

    const size_t PB = (size_t)2048 * 1024;     // per-batch elements
    ushort* qb  = (ushort*)d_ws;               // 4 MB bf16 q  [H,T,HD]
    ushort* kb  = qb + PB;                     // 4 MB bf16 k  [H,T,HD]
    ushort* vtb = kb + PB;                     // 4 MB bf16 v^T[H,HD,T]
    ushort* yb  = vtb + PB;                    // 4 MB bf16 y  [T,C]

    for (int b = 0; b < 2; b++) {
        gemm1_qkv_k<<<dim3(24, 16), 256, 0, stream>>>(x + b * PB, Wa, qb, kb, vtb);
        rope_k<<<dim3(8192), 256, 0, stream>>>(qb, kb);
        attn_k<<<dim3(512), 256, 0, stream>>>(qb, kb, vtb, yb);
        gemm2_proj_k<<<dim3(8, 16), 256, 0, stream>>>(yb, Wp, out + b * PB);
    }
}

// Round 9
// 547.211 us; speedup vs baseline: 7.2252x; 1.1212x over previous
//
#include <hip/hip_runtime.h>

// ---------------------------------------------------------------------------
// qkv = x@W_attn; RoPE(q,k); flash-attn; y@W_proj
// B=2, T=2048, C=1024, H=16, HD=64.  I/O fp32; internal tensors bf16.
//
// R9: gemm1 + gemm2 software-pipelined (register prefetch of next K-tile);
// gemm2 retiled 64x128 so grid = 256 blocks (was 128 — half the GPU idle).
// attn (MFMA QK^T + MFMA PV, verified R8) and rope (f64 trig — R4's sincosf
// is empirically implicated in the 1.068 failure, do not reintroduce).
// ---------------------------------------------------------------------------

typedef __attribute__((ext_vector_type(8))) short short8;   // 8 bf16 = 4 VGPRs
typedef __attribute__((ext_vector_type(4))) float floatx4;  // MFMA C/D frag

__device__ __forceinline__ ushort f2bf(float f) {
    unsigned x = __float_as_uint(f);
    x += 0x7fffu + ((x >> 16) & 1u);   // round-to-nearest-even
    return (ushort)(x >> 16);
}
__device__ __forceinline__ float bf2f(ushort u) {
    return __uint_as_float(((unsigned)u) << 16);
}

#define MFMA16(a, b, c) __builtin_amdgcn_mfma_f32_16x16x32_bf16((a), (b), (c), 0, 0, 0)

// ---------------------------------------------------------------------------
// GEMM1 (one batch): qkv = x_b[2048][1024](f32) @ W_attn[1024][3072](f32) ->
//   q: [H,T,HD]  k: [H,T,HD]  v^T: [H,HD,T]  (bf16)
// Pipelined: next tile's global loads prefetched into regs during MFMA phase.
// Indices/epilogue identical to the R5-R8 verified kernel.
// ---------------------------------------------------------------------------
__global__ __launch_bounds__(256, 2) void gemm1_qkv_k(const float* __restrict__ A,
                                                      const float* __restrict__ Bw,
                                                      ushort* __restrict__ qb,
                                                      ushort* __restrict__ kb,
                                                      ushort* __restrict__ vtb) {
    __shared__ __align__(16) ushort As[128][40];   // As[m][k]
    __shared__ __align__(16) ushort Bs[128][40];   // Bs[n][k]
    const int tid = threadIdx.x;
    const int m0 = blockIdx.y * 128, n0 = blockIdx.x * 128;
    const int w = tid >> 6, lane = tid & 63, quad = lane >> 4, l16 = lane & 15;
    const int wr = w >> 1, wc = w & 1;
    const int K = 1024, N = 3072;

    floatx4 acc[4][4];
#pragma unroll
    for (int mt = 0; mt < 4; mt++)
#pragma unroll
        for (int nt = 0; nt < 4; nt++) acc[mt][nt] = (floatx4){0.f, 0.f, 0.f, 0.f};

    // Prologue: prefetch K-tile 0
    float4 aR[4], bR[4];
#pragma unroll
    for (int j = 0; j < 4; j++) {
        int flat = (tid + j * 256) * 4;
        aR[j] = *(const float4*)&A[(size_t)(m0 + (flat >> 5)) * K + (flat & 31)];
        bR[j] = *(const float4*)&Bw[(size_t)(flat >> 7) * N + n0 + (flat & 127)];
    }

    for (int k0 = 0; k0 < K; k0 += 32) {
        __syncthreads();   // (A) prior tile consumed
#pragma unroll
        for (int j = 0; j < 4; j++) {
            int flat = (tid + j * 256) * 4;
            int r = flat >> 5, c = flat & 31;
            float4 t4 = aR[j];
            *(ushort4*)&As[r][c] = make_ushort4(f2bf(t4.x), f2bf(t4.y), f2bf(t4.z), f2bf(t4.w));
            int bk = flat >> 7, bn = flat & 127;
            float4 u4 = bR[j];
            Bs[bn + 0][bk] = f2bf(u4.x);
            Bs[bn + 1][bk] = f2bf(u4.y);
            Bs[bn + 2][bk] = f2bf(u4.z);
            Bs[bn + 3][bk] = f2bf(u4.w);
        }
        // Prefetch next tile (in flight during MFMA phase)
        if (k0 + 32 < K) {
#pragma unroll
            for (int j = 0; j < 4; j++) {
                int flat = (tid + j * 256) * 4;
                aR[j] = *(const float4*)&A[(size_t)(m0 + (flat >> 5)) * K + (k0 + 32) + (flat & 31)];
                bR[j] = *(const float4*)&Bw[(size_t)(k0 + 32 + (flat >> 7)) * N + n0 + (flat & 127)];
            }
        }
        __syncthreads();   // (B) staging visible
        short8 af[4], bfr[4];
#pragma unroll
        for (int mt = 0; mt < 4; mt++) af[mt] = *(short8*)&As[wr * 64 + mt * 16 + l16][quad * 8];
#pragma unroll
        for (int nt = 0; nt < 4; nt++) bfr[nt] = *(short8*)&Bs[wc * 64 + nt * 16 + l16][quad * 8];
#pragma unroll
        for (int mt = 0; mt < 4; mt++)
#pragma unroll
            for (int nt = 0; nt < 4; nt++) acc[mt][nt] = MFMA16(af[mt], bfr[nt], acc[mt][nt]);
    }

    // Epilogue [verified R5-R8]
#pragma unroll
    for (int nt = 0; nt < 4; nt++) {
        const int n = n0 + wc * 64 + nt * 16 + l16;
        const int seg = n >> 10;          // 0=q 1=k 2=v
        const int cn = n & 1023;
        const int h = cn >> 6, d = cn & 63;
#pragma unroll
        for (int mt = 0; mt < 4; mt++) {
#pragma unroll
            for (int r = 0; r < 4; r++) {
                const int t = m0 + wr * 64 + mt * 16 + quad * 4 + r;
                const ushort v = f2bf(acc[mt][nt][r]);
                if (seg == 0)      qb[((size_t)h * 2048 + t) * 64 + d] = v;
                else if (seg == 1) kb[((size_t)h * 2048 + t) * 64 + d] = v;
                else               vtb[((size_t)h * 64 + d) * 2048 + t] = v;
            }
        }
    }
}

// ---------------------------------------------------------------------------
// RoPE (roll variant), f64 trig  [verified R5-R8; sincosf implicated in R4]
// ---------------------------------------------------------------------------
__global__ __launch_bounds__(256) void rope_k(ushort* __restrict__ q, ushort* __restrict__ k) {
    const int wid = blockIdx.x * 4 + (threadIdx.x >> 6);  // row = h*2048 + t
    const int lane = threadIdx.x & 63;
    const int t = wid & 2047;
    const int j = lane & 31;
    const double inv = pow(10000.0, -(double)j / 32.0);
    const double ang = (double)t * inv;
    const float c = (float)cos(ang);
    const float s = (float)sin(ang);
    const size_t base = (size_t)wid * 64;

    float qv = bf2f(q[base + lane]);
    float qp = __shfl(qv, (lane + 63) & 63, 64);
    q[base + lane] = f2bf(qv * c + qp * s);

    float kv = bf2f(k[base + lane]);
    float kp = __shfl(kv, (lane + 63) & 63, 64);
    k[base + lane] = f2bf(kv * c + kp * s);
}

// ---------------------------------------------------------------------------
// Flash attention (causal), one batch  [verified R8 — unchanged]
// ---------------------------------------------------------------------------
__global__ __launch_bounds__(256, 2) void attn_k(const ushort* __restrict__ q,
                                                 const ushort* __restrict__ k,
                                                 const ushort* __restrict__ vt,
                                                 ushort* __restrict__ y) {
    __shared__ __align__(16) ushort Ks[64][72];   // [key][d]  bf16
    __shared__ __align__(16) ushort Vs[64][72];   // [d][key]  bf16 (V^T)
    __shared__ __align__(16) ushort Ps[4][16][72];// per-wave P [row][key] bf16

    const int qt = 31 - (blockIdx.x & 31);        // big tiles first
    const int h = blockIdx.x >> 5;
    const int tid = threadIdx.x, w = tid >> 6, lane = tid & 63;
    const int quad = lane >> 4, l16 = lane & 15;
    const int q0 = qt * 64;

    short8 qa0, qa1;
    {
        const int qrow = q0 + w * 16 + l16;
        const ushort* qp = q + ((size_t)h * 2048 + qrow) * 64 + quad * 8;
        qa0 = *(const short8*)(qp);
        qa1 = *(const short8*)(qp + 32);
    }

    floatx4 O[4];
#pragma unroll
    for (int dt = 0; dt < 4; dt++) O[dt] = (floatx4){0.f, 0.f, 0.f, 0.f};
    float M[4] = {-30000.f, -30000.f, -30000.f, -30000.f};
    float L[4] = {0.f, 0.f, 0.f, 0.f};

    for (int kt = 0; kt <= qt; kt++) {
        const int kbase = kt * 64;
        __syncthreads();   // (A) prior tile fully consumed
#pragma unroll
        for (int jj = 0; jj < 2; jj++) {
            int flat = (tid + jj * 256) * 8;
            int r = flat >> 6, c = flat & 63;
            *(uint4*)&Ks[r][c] = *(const uint4*)&k[((size_t)h * 2048 + kbase + r) * 64 + c];
            *(uint4*)&Vs[r][c] = *(const uint4*)&vt[((size_t)h * 64 + r) * 2048 + kbase + c];
        }
        __syncthreads();   // (B) staging complete

        floatx4 s[4];
#pragma unroll
        for (int nt = 0; nt < 4; nt++) {
            short8 kb0 = *(short8*)&Ks[nt * 16 + l16][quad * 8];
            short8 kb1 = *(short8*)&Ks[nt * 16 + l16][32 + quad * 8];
            floatx4 z = (floatx4){0.f, 0.f, 0.f, 0.f};
            z = MFMA16(qa0, kb0, z);
            z = MFMA16(qa1, kb1, z);
            s[nt] = z;
        }

        const bool diag = (kt == qt);
#pragma unroll
        for (int nt = 0; nt < 4; nt++) {
            const int kidx = kbase + nt * 16 + l16;
#pragma unroll
            for (int r = 0; r < 4; r++) {
                float vv = s[nt][r] * 0.125f;   // 1/sqrt(64)
                if (diag) {
                    const int qi = q0 + w * 16 + quad * 4 + r;
                    if (kidx > qi) vv = -30000.f;
                }
                s[nt][r] = vv;
            }
        }

#pragma unroll
        for (int r = 0; r < 4; r++) {
            float mx = fmaxf(fmaxf(s[0][r], s[1][r]), fmaxf(s[2][r], s[3][r]));
            mx = fmaxf(mx, __shfl_xor(mx, 1, 64));
            mx = fmaxf(mx, __shfl_xor(mx, 2, 64));
            mx = fmaxf(mx, __shfl_xor(mx, 4, 64));
            mx = fmaxf(mx, __shfl_xor(mx, 8, 64));
            const float Mn = fmaxf(M[r], mx);
            const float alpha = __expf(M[r] - Mn);
            float sum = 0.f;
#pragma unroll
            for (int nt = 0; nt < 4; nt++) {
                float p = __expf(s[nt][r] - Mn);
                s[nt][r] = p;
                sum += p;
            }
            sum += __shfl_xor(sum, 1, 64);
            sum += __shfl_xor(sum, 2, 64);
            sum += __shfl_xor(sum, 4, 64);
            sum += __shfl_xor(sum, 8, 64);
            L[r] = L[r] * alpha + sum;
            M[r] = Mn;
#pragma unroll
            for (int dt = 0; dt < 4; dt++) O[dt][r] *= alpha;
        }

#pragma unroll
        for (int nt = 0; nt < 4; nt++)
#pragma unroll
            for (int r = 0; r < 4; r++)
                Ps[w][quad * 4 + r][nt * 16 + l16] = f2bf(s[nt][r]);
        __syncthreads();   // (C) P visible

        short8 pa0 = *(short8*)&Ps[w][l16][quad * 8];
        short8 pa1 = *(short8*)&Ps[w][l16][32 + quad * 8];
#pragma unroll
        for (int dt = 0; dt < 4; dt++) {
            short8 vb0 = *(short8*)&Vs[dt * 16 + l16][quad * 8];
            short8 vb1 = *(short8*)&Vs[dt * 16 + l16][32 + quad * 8];
            O[dt] = MFMA16(pa0, vb0, O[dt]);
            O[dt] = MFMA16(pa1, vb1, O[dt]);
        }
    }

#pragma unroll
    for (int dt = 0; dt < 4; dt++)
#pragma unroll
        for (int r = 0; r < 4; r++) {
            const int t = q0 + w * 16 + quad * 4 + r;
            const float val = O[dt][r] / L[r];
            y[((size_t)t) * 1024 + h * 64 + dt * 16 + l16] = f2bf(val);
        }
}

// ---------------------------------------------------------------------------
// GEMM2 (one batch): out(f32) = y[2048][1024](bf16) @ W_proj[1024][1024](f32)
// Retiled 64x128 (grid 8x32 = 256 blocks, 1/CU) + register prefetch pipeline.
// Waves: wr=w>>1 owns 32-row half, wc=w&1 owns 64-col half; acc[2][4].
// ---------------------------------------------------------------------------
__global__ __launch_bounds__(256, 2) void gemm2_proj_k(const ushort* __restrict__ Y,
                                                       const float* __restrict__ Bw,
                                                       float* __restrict__ out) {
    __shared__ __align__(16) ushort As[64][40];    // [m][k]
    __shared__ __align__(16) ushort Bs[128][40];   // [n][k]
    const int tid = threadIdx.x;
    const int m0 = blockIdx.y * 64, n0 = blockIdx.x * 128;
    const int w = tid >> 6, lane = tid & 63, quad = lane >> 4, l16 = lane & 15;
    const int wr = w >> 1, wc = w & 1;
    const int K = 1024, N = 1024;

    floatx4 acc[2][4];
#pragma unroll
    for (int mt = 0; mt < 2; mt++)
#pragma unroll
        for (int nt = 0; nt < 4; nt++) acc[mt][nt] = (floatx4){0.f, 0.f, 0.f, 0.f};

    // Prologue: prefetch K-tile 0.  A: 64x32 bf16 (1 uint4/thread); B: 32x128 f32.
    uint4 aR;
    float4 bR[4];
    {
        int flat = tid * 8;
        aR = *(const uint4*)&Y[(size_t)(m0 + (flat >> 5)) * K + (flat & 31)];
#pragma unroll
        for (int j = 0; j < 4; j++) {
            int f2 = (tid + j * 256) * 4;
            bR[j] = *(const float4*)&Bw[(size_t)(f2 >> 7) * N + n0 + (f2 & 127)];
        }
    }

    for (int k0 = 0; k0 < K; k0 += 32) {
        __syncthreads();
        {
            int flat = tid * 8;
            *(uint4*)&As[flat >> 5][flat & 31] = aR;
#pragma unroll
            for (int j = 0; j < 4; j++) {
                int f2 = (tid + j * 256) * 4;
                int bk = f2 >> 7, bn = f2 & 127;
                float4 u4 = bR[j];
                Bs[bn + 0][bk] = f2bf(u4.x);
                Bs[bn + 1][bk] = f2bf(u4.y);
                Bs[bn + 2][bk] = f2bf(u4.z);
                Bs[bn + 3][bk] = f2bf(u4.w);
            }
        }
        if (k0 + 32 < K) {
            int flat = tid * 8;
            aR = *(const uint4*)&Y[(size_t)(m0 + (flat >> 5)) * K + (k0 + 32) + (flat & 31)];
#pragma unroll
            for (int j = 0; j < 4; j++) {
                int f2 = (tid + j * 256) * 4;
                bR[j] = *(const float4*)&Bw[(size_t)(k0 + 32 + (f2 >> 7)) * N + n0 + (f2 & 127)];
            }
        }
        __syncthreads();
        short8 af[2], bfr[4];
#pragma unroll
        for (int mt = 0; mt < 2; mt++) af[mt] = *(short8*)&As[wr * 32 + mt * 16 + l16][quad * 8];
#pragma unroll
        for (int nt = 0; nt < 4; nt++) bfr[nt] = *(short8*)&Bs[wc * 64 + nt * 16 + l16][quad * 8];
#pragma unroll
        for (int mt = 0; mt < 2; mt++)
#pragma unroll
            for (int nt = 0; nt < 4; nt++) acc[mt][nt] = MFMA16(af[mt], bfr[nt], acc[mt][nt]);
    }

#pragma unroll
    for (int mt = 0; mt < 2; mt++)
#pragma unroll
        for (int nt = 0; nt < 4; nt++) {
            const int n = n0 + wc * 64 + nt * 16 + l16;
#pragma unroll
            for (int r = 0; r < 4; r++) {
                const int m = m0 + wr * 32 + mt * 16 + quad * 4 + r;
                out[(size_t)m * 1024 + n] = acc[mt][nt][r];
            }
        }
}

// ---------------------------------------------------------------------------
extern "C" void kernel_launch(void* const* d_in, const int* in_sizes, int n_in,
                              void* d_out, int out_size, void* d_ws, size_t ws_size,
                              hipStream_t stream) {
    const float* x  = (const float*)d_in[0];   // [2,2048,1024] f32
    const float* Wa = (const float*)d_in[1];   // [1024,3072]  f32
    const float* Wp = (const float*)d_in[2];   // [1024,1024]  f32
    float* out = (float*)d_out;                // [2,2048,1024] f32

    const size_t PB = (size_t)2048 * 1024;     // per-batch elements
    ushort* qb  = (ushort*)d_ws;               // 4 MB bf16 q  [H,T,HD]
    ushort* kb  = qb + PB;                     // 4 MB bf16 k  [H,T,HD]
    ushort* vtb = kb + PB;                     // 4 MB bf16 v^T[H,HD,T]
    ushort* yb  = vtb + PB;                    // 4 MB bf16 y  [T,C]

    for (int b = 0; b < 2; b++) {
        gemm1_qkv_k<<<dim3(24, 16), 256, 0, stream>>>(x + b * PB, Wa, qb, kb, vtb);
        rope_k<<<dim3(8192), 256, 0, stream>>>(qb, kb);
        attn_k<<<dim3(512), 256, 0, stream>>>(qb, kb, vtb, yb);
        gemm2_proj_k<<<dim3(8, 32), 256, 0, stream>>>(yb, Wp, out + b * PB);
    }
}

// Round 10
// 467.454 us; speedup vs baseline: 8.4580x; 1.1706x over previous
//
#include <hip/hip_runtime.h>

// ---------------------------------------------------------------------------
// qkv = x@W_attn; RoPE(q,k); flash-attn; y@W_proj
// B=2, T=2048, C=1024, H=16, HD=64.  I/O fp32; internal tensors bf16.
//
// R10: attention rewritten transposed (S^T = K·Q^T, O^T = V^T·P^T) — softmax
// needs 2 shuffles instead of 32, P^T written as b64 packs; q-tiles paired
// (p, 31-p) per block => 33 K-tiles/block, grid 256 = perfectly balanced.
// Fragment loads identical to the R8-HW-verified mappings (operands swapped).
// gemm1/rope/gemm2 unchanged (R9-verified).  RoPE keeps f64 trig (sincosf
// implicated in R4's failure).
// ---------------------------------------------------------------------------

typedef __attribute__((ext_vector_type(8))) short short8;   // 8 bf16 = 4 VGPRs
typedef __attribute__((ext_vector_type(4))) float floatx4;  // MFMA C/D frag

__device__ __forceinline__ ushort f2bf(float f) {
    unsigned x = __float_as_uint(f);
    x += 0x7fffu + ((x >> 16) & 1u);   // round-to-nearest-even
    return (ushort)(x >> 16);
}
__device__ __forceinline__ float bf2f(ushort u) {
    return __uint_as_float(((unsigned)u) << 16);
}

#define MFMA16(a, b, c) __builtin_amdgcn_mfma_f32_16x16x32_bf16((a), (b), (c), 0, 0, 0)

// ---------------------------------------------------------------------------
// GEMM1 (one batch): qkv = x_b[2048][1024](f32) @ W_attn[1024][3072](f32) ->
//   q: [H,T,HD]  k: [H,T,HD]  v^T: [H,HD,T]  (bf16)   [verified R9]
// ---------------------------------------------------------------------------
__global__ __launch_bounds__(256, 2) void gemm1_qkv_k(const float* __restrict__ A,
                                                      const float* __restrict__ Bw,
                                                      ushort* __restrict__ qb,
                                                      ushort* __restrict__ kb,
                                                      ushort* __restrict__ vtb) {
    __shared__ __align__(16) ushort As[128][40];   // As[m][k]
    __shared__ __align__(16) ushort Bs[128][40];   // Bs[n][k]
    const int tid = threadIdx.x;
    const int m0 = blockIdx.y * 128, n0 = blockIdx.x * 128;
    const int w = tid >> 6, lane = tid & 63, quad = lane >> 4, l16 = lane & 15;
    const int wr = w >> 1, wc = w & 1;
    const int K = 1024, N = 3072;

    floatx4 acc[4][4];
#pragma unroll
    for (int mt = 0; mt < 4; mt++)
#pragma unroll
        for (int nt = 0; nt < 4; nt++) acc[mt][nt] = (floatx4){0.f, 0.f, 0.f, 0.f};

    float4 aR[4], bR[4];
#pragma unroll
    for (int j = 0; j < 4; j++) {
        int flat = (tid + j * 256) * 4;
        aR[j] = *(const float4*)&A[(size_t)(m0 + (flat >> 5)) * K + (flat & 31)];
        bR[j] = *(const float4*)&Bw[(size_t)(flat >> 7) * N + n0 + (flat & 127)];
    }

    for (int k0 = 0; k0 < K; k0 += 32) {
        __syncthreads();
#pragma unroll
        for (int j = 0; j < 4; j++) {
            int flat = (tid + j * 256) * 4;
            int r = flat >> 5, c = flat & 31;
            float4 t4 = aR[j];
            *(ushort4*)&As[r][c] = make_ushort4(f2bf(t4.x), f2bf(t4.y), f2bf(t4.z), f2bf(t4.w));
            int bk = flat >> 7, bn = flat & 127;
            float4 u4 = bR[j];
            Bs[bn + 0][bk] = f2bf(u4.x);
            Bs[bn + 1][bk] = f2bf(u4.y);
            Bs[bn + 2][bk] = f2bf(u4.z);
            Bs[bn + 3][bk] = f2bf(u4.w);
        }
        if (k0 + 32 < K) {
#pragma unroll
            for (int j = 0; j < 4; j++) {
                int flat = (tid + j * 256) * 4;
                aR[j] = *(const float4*)&A[(size_t)(m0 + (flat >> 5)) * K + (k0 + 32) + (flat & 31)];
                bR[j] = *(const float4*)&Bw[(size_t)(k0 + 32 + (flat >> 7)) * N + n0 + (flat & 127)];
            }
        }
        __syncthreads();
        short8 af[4], bfr[4];
#pragma unroll
        for (int mt = 0; mt < 4; mt++) af[mt] = *(short8*)&As[wr * 64 + mt * 16 + l16][quad * 8];
#pragma unroll
        for (int nt = 0; nt < 4; nt++) bfr[nt] = *(short8*)&Bs[wc * 64 + nt * 16 + l16][quad * 8];
#pragma unroll
        for (int mt = 0; mt < 4; mt++)
#pragma unroll
            for (int nt = 0; nt < 4; nt++) acc[mt][nt] = MFMA16(af[mt], bfr[nt], acc[mt][nt]);
    }

#pragma unroll
    for (int nt = 0; nt < 4; nt++) {
        const int n = n0 + wc * 64 + nt * 16 + l16;
        const int seg = n >> 10;          // 0=q 1=k 2=v
        const int cn = n & 1023;
        const int h = cn >> 6, d = cn & 63;
#pragma unroll
        for (int mt = 0; mt < 4; mt++) {
#pragma unroll
            for (int r = 0; r < 4; r++) {
                const int t = m0 + wr * 64 + mt * 16 + quad * 4 + r;
                const ushort v = f2bf(acc[mt][nt][r]);
                if (seg == 0)      qb[((size_t)h * 2048 + t) * 64 + d] = v;
                else if (seg == 1) kb[((size_t)h * 2048 + t) * 64 + d] = v;
                else               vtb[((size_t)h * 64 + d) * 2048 + t] = v;
            }
        }
    }
}

// ---------------------------------------------------------------------------
// RoPE (roll variant), f64 trig  [verified R5-R9]
// ---------------------------------------------------------------------------
__global__ __launch_bounds__(256) void rope_k(ushort* __restrict__ q, ushort* __restrict__ k) {
    const int wid = blockIdx.x * 4 + (threadIdx.x >> 6);  // row = h*2048 + t
    const int lane = threadIdx.x & 63;
    const int t = wid & 2047;
    const int j = lane & 31;
    const double inv = pow(10000.0, -(double)j / 32.0);
    const double ang = (double)t * inv;
    const float c = (float)cos(ang);
    const float s = (float)sin(ang);
    const size_t base = (size_t)wid * 64;

    float qv = bf2f(q[base + lane]);
    float qp = __shfl(qv, (lane + 63) & 63, 64);
    q[base + lane] = f2bf(qv * c + qp * s);

    float kv = bf2f(k[base + lane]);
    float kp = __shfl(kv, (lane + 63) & 63, 64);
    k[base + lane] = f2bf(kv * c + kp * s);
}

// ---------------------------------------------------------------------------
// Flash attention (causal), one batch, TRANSPOSED form.
// Block = (h, pair p): processes q-tiles p and 31-p sequentially (33 K-tiles
// total, balanced).  4 waves; wave w owns qrows [qt*64 + w*16, +16).
// S^T = K·Q^T: C-layout col=qrow(l16), row=key(quad*4+r) -> softmax over keys
// = in-lane reduce + shfl_xor(16,32).  O^T = V^T·P^T accumulated in C-layout.
// ---------------------------------------------------------------------------
__global__ __launch_bounds__(256, 2) void attn_k(const ushort* __restrict__ q,
                                                 const ushort* __restrict__ k,
                                                 const ushort* __restrict__ vt,
                                                 ushort* __restrict__ y) {
    __shared__ __align__(16) ushort Ks[64][72];    // [key][d]  bf16
    __shared__ __align__(16) ushort Vs[64][72];    // [d][key]  bf16 (V^T)
    __shared__ __align__(16) ushort Ps[4][16][72]; // per-wave P^T as [qrow][key]

    const int p = blockIdx.x & 15;
    const int h = blockIdx.x >> 4;
    const int tid = threadIdx.x, w = tid >> 6, lane = tid & 63;
    const int quad = lane >> 4, l16 = lane & 15;

    for (int phase = 0; phase < 2; phase++) {
        const int qt = phase ? (31 - p) : p;
        const int q0 = qt * 64;
        const int qrow = q0 + w * 16 + l16;      // this lane's q-row (= St col)

        short8 qa0, qa1;
        {
            const ushort* qp = q + ((size_t)h * 2048 + qrow) * 64 + quad * 8;
            qa0 = *(const short8*)(qp);
            qa1 = *(const short8*)(qp + 32);
        }

        floatx4 O[4];
#pragma unroll
        for (int dt = 0; dt < 4; dt++) O[dt] = (floatx4){0.f, 0.f, 0.f, 0.f};
        float M = -30000.f, L = 0.f;

        for (int kt = 0; kt <= qt; kt++) {
            const int kbase = kt * 64;
            __syncthreads();   // (A) prior tile fully consumed (incl. prior phase)
#pragma unroll
            for (int jj = 0; jj < 2; jj++) {
                int flat = (tid + jj * 256) * 8;
                int r = flat >> 6, c = flat & 63;
                *(uint4*)&Ks[r][c] = *(const uint4*)&k[((size_t)h * 2048 + kbase + r) * 64 + c];
                *(uint4*)&Vs[r][c] = *(const uint4*)&vt[((size_t)h * 64 + r) * 2048 + kbase + c];
            }
            __syncthreads();   // (B) staging complete

            // S^T = K·Q^T  (A = K frag, B = Q frag — same loads as R8, swapped)
            floatx4 s[4];
#pragma unroll
            for (int nt = 0; nt < 4; nt++) {
                short8 ka0 = *(short8*)&Ks[nt * 16 + l16][quad * 8];
                short8 ka1 = *(short8*)&Ks[nt * 16 + l16][32 + quad * 8];
                floatx4 z = (floatx4){0.f, 0.f, 0.f, 0.f};
                z = MFMA16(ka0, qa0, z);
                z = MFMA16(ka1, qa1, z);
                s[nt] = z;
            }

            // scale + causal mask (key = kbase + nt*16 + quad*4 + r)
            const bool diag = (kt == qt);
#pragma unroll
            for (int nt = 0; nt < 4; nt++)
#pragma unroll
                for (int r = 0; r < 4; r++) {
                    float vv = s[nt][r] * 0.125f;   // 1/sqrt(64)
                    if (diag) {
                        const int kidx = kbase + nt * 16 + quad * 4 + r;
                        if (kidx > qrow) vv = -30000.f;
                    }
                    s[nt][r] = vv;
                }

            // online softmax over keys: in-lane 16 + cross-quad (xor 16, 32)
            float mx = -30000.f;
#pragma unroll
            for (int nt = 0; nt < 4; nt++)
#pragma unroll
                for (int r = 0; r < 4; r++) mx = fmaxf(mx, s[nt][r]);
            mx = fmaxf(mx, __shfl_xor(mx, 16, 64));
            mx = fmaxf(mx, __shfl_xor(mx, 32, 64));
            const float Mn = fmaxf(M, mx);
            const float alpha = __expf(M - Mn);
            float sum = 0.f;
#pragma unroll
            for (int nt = 0; nt < 4; nt++)
#pragma unroll
                for (int r = 0; r < 4; r++) {
                    float pv = __expf(s[nt][r] - Mn);
                    s[nt][r] = pv;
                    sum += pv;
                }
            sum += __shfl_xor(sum, 16, 64);
            sum += __shfl_xor(sum, 32, 64);
            L = L * alpha + sum;
            M = Mn;
#pragma unroll
            for (int dt = 0; dt < 4; dt++) O[dt] *= alpha;

            // P^T -> LDS as [qrow][key]: 4 contiguous keys per (nt) => b64
#pragma unroll
            for (int nt = 0; nt < 4; nt++) {
                ushort4 pk = make_ushort4(f2bf(s[nt][0]), f2bf(s[nt][1]),
                                          f2bf(s[nt][2]), f2bf(s[nt][3]));
                *(ushort4*)&Ps[w][l16][nt * 16 + quad * 4] = pk;
            }
            __syncthreads();   // (C) P visible

            // O^T += V^T·P^T  (A = V^T frag, B = P^T frag)
            short8 pb0 = *(short8*)&Ps[w][l16][quad * 8];
            short8 pb1 = *(short8*)&Ps[w][l16][32 + quad * 8];
#pragma unroll
            for (int dt = 0; dt < 4; dt++) {
                short8 va0 = *(short8*)&Vs[dt * 16 + l16][quad * 8];
                short8 va1 = *(short8*)&Vs[dt * 16 + l16][32 + quad * 8];
                O[dt] = MFMA16(va0, pb0, O[dt]);
                O[dt] = MFMA16(va1, pb1, O[dt]);
            }
        }

        // Epilogue: O^T C-layout: d = dt*16 + quad*4 + r (4 contiguous), t = qrow
        const float rl = 1.0f / L;
#pragma unroll
        for (int dt = 0; dt < 4; dt++) {
            ushort4 o4 = make_ushort4(f2bf(O[dt][0] * rl), f2bf(O[dt][1] * rl),
                                      f2bf(O[dt][2] * rl), f2bf(O[dt][3] * rl));
            *(ushort4*)&y[(size_t)qrow * 1024 + h * 64 + dt * 16 + quad * 4] = o4;
        }
    }
}

// ---------------------------------------------------------------------------
// GEMM2 (one batch): out(f32) = y[2048][1024](bf16) @ W_proj[1024][1024](f32)
// 64x128 tile, register prefetch  [verified R9]
// ---------------------------------------------------------------------------
__global__ __launch_bounds__(256, 2) void gemm2_proj_k(const ushort* __restrict__ Y,
                                                       const float* __restrict__ Bw,
                                                       float* __restrict__ out) {
    __shared__ __align__(16) ushort As[64][40];    // [m][k]
    __shared__ __align__(16) ushort Bs[128][40];   // [n][k]
    const int tid = threadIdx.x;
    const int m0 = blockIdx.y * 64, n0 = blockIdx.x * 128;
    const int w = tid >> 6, lane = tid & 63, quad = lane >> 4, l16 = lane & 15;
    const int wr = w >> 1, wc = w & 1;
    const int K = 1024, N = 1024;

    floatx4 acc[2][4];
#pragma unroll
    for (int mt = 0; mt < 2; mt++)
#pragma unroll
        for (int nt = 0; nt < 4; nt++) acc[mt][nt] = (floatx4){0.f, 0.f, 0.f, 0.f};

    uint4 aR;
    float4 bR[4];
    {
        int flat = tid * 8;
        aR = *(const uint4*)&Y[(size_t)(m0 + (flat >> 5)) * K + (flat & 31)];
#pragma unroll
        for (int j = 0; j < 4; j++) {
            int f2 = (tid + j * 256) * 4;
            bR[j] = *(const float4*)&Bw[(size_t)(f2 >> 7) * N + n0 + (f2 & 127)];
        }
    }

    for (int k0 = 0; k0 < K; k0 += 32) {
        __syncthreads();
        {
            int flat = tid * 8;
            *(uint4*)&As[flat >> 5][flat & 31] = aR;
#pragma unroll
            for (int j = 0; j < 4; j++) {
                int f2 = (tid + j * 256) * 4;
                int bk = f2 >> 7, bn = f2 & 127;
                float4 u4 = bR[j];
                Bs[bn + 0][bk] = f2bf(u4.x);
                Bs[bn + 1][bk] = f2bf(u4.y);
                Bs[bn + 2][bk] = f2bf(u4.z);
                Bs[bn + 3][bk] = f2bf(u4.w);
            }
        }
        if (k0 + 32 < K) {
            int flat = tid * 8;
            aR = *(const uint4*)&Y[(size_t)(m0 + (flat >> 5)) * K + (k0 + 32) + (flat & 31)];
#pragma unroll
            for (int j = 0; j < 4; j++) {
                int f2 = (tid + j * 256) * 4;
                bR[j] = *(const float4*)&Bw[(size_t)(k0 + 32 + (f2 >> 7)) * N + n0 + (f2 & 127)];
            }
        }
        __syncthreads();
        short8 af[2], bfr[4];
#pragma unroll
        for (int mt = 0; mt < 2; mt++) af[mt] = *(short8*)&As[wr * 32 + mt * 16 + l16][quad * 8];
#pragma unroll
        for (int nt = 0; nt < 4; nt++) bfr[nt] = *(short8*)&Bs[wc * 64 + nt * 16 + l16][quad * 8];
#pragma unroll
        for (int mt = 0; mt < 2; mt++)
#pragma unroll
            for (int nt = 0; nt < 4; nt++) acc[mt][nt] = MFMA16(af[mt], bfr[nt], acc[mt][nt]);
    }

#pragma unroll
    for (int mt = 0; mt < 2; mt++)
#pragma unroll
        for (int nt = 0; nt < 4; nt++) {
            const int n = n0 + wc * 64 + nt * 16 + l16;
#pragma unroll
            for (int r = 0; r < 4; r++) {
                const int m = m0 + wr * 32 + mt * 16 + quad * 4 + r;
                out[(size_t)m * 1024 + n] = acc[mt][nt][r];
            }
        }
}

// ---------------------------------------------------------------------------
extern "C" void kernel_launch(void* const* d_in, const int* in_sizes, int n_in,
                              void* d_out, int out_size, void* d_ws, size_t ws_size,
                              hipStream_t stream) {
    const float* x  = (const float*)d_in[0];   // [2,2048,1024] f32
    const float* Wa = (const float*)d_in[1];   // [1024,3072]  f32
    const float* Wp = (const float*)d_in[2];   // [1024,1024]  f32
    float* out = (float*)d_out;                // [2,2048,1024] f32

    const size_t PB = (size_t)2048 * 1024;     // per-batch elements
    ushort* qb  = (ushort*)d_ws;               // 4 MB bf16 q  [H,T,HD]
    ushort* kb  = qb + PB;                     // 4 MB bf16 k  [H,T,HD]
    ushort* vtb = kb + PB;                     // 4 MB bf16 v^T[H,HD,T]
    ushort* yb  = vtb + PB;                    // 4 MB bf16 y  [T,C]

    for (int b = 0; b < 2; b++) {
        gemm1_qkv_k<<<dim3(24, 16), 256, 0, stream>>>(x + b * PB, Wa, qb, kb, vtb);
        rope_k<<<dim3(8192), 256, 0, stream>>>(qb, kb);
        attn_k<<<dim3(256), 256, 0, stream>>>(qb, kb, vtb, yb);
        gemm2_proj_k<<<dim3(8, 32), 256, 0, stream>>>(yb, Wp, out + b * PB);
    }
}

// Round 11
// 465.884 us; speedup vs baseline: 8.4865x; 1.0034x over previous
//
#include <hip/hip_runtime.h>

// ---------------------------------------------------------------------------
// qkv = x@W_attn; RoPE(q,k); flash-attn; y@W_proj
// B=2, T=2048, C=1024, H=16, HD=64.  I/O fp32; internal tensors bf16.
//
// R11: weights pre-transposed+converted to bf16 once per launch (tp kernel);
// x pre-converted per batch (cvt).  GEMM staging is now pure uint4 copies
// (conflict-free — the in-kernel B transpose was a 32-way-conflict scalar
// scatter, 2.6e7 SQ_LDS_BANK_CONFLICT).  W^T_attn lives in d_out's b1 half
// (fully overwritten by gemm2-b1 after last use); W^T_proj regenerated into
// the dead qb slot before each gemm2; x_bf16 in the dead yb slot.
// attn (R10-verified transposed form) and rope (f64 trig) unchanged.
// ---------------------------------------------------------------------------

typedef __attribute__((ext_vector_type(8))) short short8;   // 8 bf16 = 4 VGPRs
typedef __attribute__((ext_vector_type(4))) float floatx4;  // MFMA C/D frag

__device__ __forceinline__ ushort f2bf(float f) {
    unsigned x = __float_as_uint(f);
    x += 0x7fffu + ((x >> 16) & 1u);   // round-to-nearest-even
    return (ushort)(x >> 16);
}
__device__ __forceinline__ float bf2f(ushort u) {
    return __uint_as_float(((unsigned)u) << 16);
}

#define MFMA16(a, b, c) __builtin_amdgcn_mfma_f32_16x16x32_bf16((a), (b), (c), 0, 0, 0)

// ---------------------------------------------------------------------------
// Transpose + cvt: src f32 [R][C] -> dst bf16 [C][R].  32x32 tiles via LDS.
// ---------------------------------------------------------------------------
__global__ __launch_bounds__(256) void tp_k(const float* __restrict__ src,
                                            ushort* __restrict__ dst,
                                            int R, int C) {
    __shared__ ushort t[32][34];
    const int c0 = blockIdx.x * 32, r0 = blockIdx.y * 32;
    const int tr = threadIdx.x >> 5, tc = threadIdx.x & 31;
#pragma unroll
    for (int j = 0; j < 4; j++)
        t[tr + j * 8][tc] = f2bf(src[(size_t)(r0 + tr + j * 8) * C + c0 + tc]);
    __syncthreads();
#pragma unroll
    for (int j = 0; j < 4; j++)
        dst[(size_t)(c0 + tr + j * 8) * R + r0 + tc] = t[tc][tr + j * 8];
}

// ---------------------------------------------------------------------------
// cvt: f32 -> bf16, 4 elems/thread.
// ---------------------------------------------------------------------------
__global__ __launch_bounds__(256) void cvt_k(const float* __restrict__ src,
                                             ushort* __restrict__ dst) {
    const size_t i = ((size_t)blockIdx.x * 256 + threadIdx.x) * 4;
    float4 t4 = *(const float4*)&src[i];
    *(ushort4*)&dst[i] = make_ushort4(f2bf(t4.x), f2bf(t4.y), f2bf(t4.z), f2bf(t4.w));
}

// ---------------------------------------------------------------------------
// GEMM1 (one batch): qkv = xb[2048][1024](bf16) @ WaT^T (Bt bf16 [3072][1024])
//   -> q: [H,T,HD]  k: [H,T,HD]  v^T: [H,HD,T]  (bf16)
// Pure uint4 staging (conflict-free), register prefetch.  Frag/epilogue math
// identical to the R5-R10 verified kernel.
// ---------------------------------------------------------------------------
__global__ __launch_bounds__(256, 2) void gemm1_qkv_k(const ushort* __restrict__ Ab,
                                                      const ushort* __restrict__ Bt,
                                                      ushort* __restrict__ qb,
                                                      ushort* __restrict__ kb,
                                                      ushort* __restrict__ vtb) {
    __shared__ __align__(16) ushort As[128][40];   // [m][k]
    __shared__ __align__(16) ushort Bs[128][40];   // [n][k]
    const int tid = threadIdx.x;
    const int m0 = blockIdx.y * 128, n0 = blockIdx.x * 128;
    const int w = tid >> 6, lane = tid & 63, quad = lane >> 4, l16 = lane & 15;
    const int wr = w >> 1, wc = w & 1;
    const int K = 1024;

    floatx4 acc[4][4];
#pragma unroll
    for (int mt = 0; mt < 4; mt++)
#pragma unroll
        for (int nt = 0; nt < 4; nt++) acc[mt][nt] = (floatx4){0.f, 0.f, 0.f, 0.f};

    uint4 aR[2], bR[2];
#pragma unroll
    for (int jj = 0; jj < 2; jj++) {
        int flat = (tid + jj * 256) * 8;
        int r = flat >> 5, c = flat & 31;
        aR[jj] = *(const uint4*)&Ab[(size_t)(m0 + r) * K + c];
        bR[jj] = *(const uint4*)&Bt[(size_t)(n0 + r) * K + c];
    }

    for (int k0 = 0; k0 < K; k0 += 32) {
        __syncthreads();
#pragma unroll
        for (int jj = 0; jj < 2; jj++) {
            int flat = (tid + jj * 256) * 8;
            int r = flat >> 5, c = flat & 31;
            *(uint4*)&As[r][c] = aR[jj];
            *(uint4*)&Bs[r][c] = bR[jj];
        }
        if (k0 + 32 < K) {
#pragma unroll
            for (int jj = 0; jj < 2; jj++) {
                int flat = (tid + jj * 256) * 8;
                int r = flat >> 5, c = flat & 31;
                aR[jj] = *(const uint4*)&Ab[(size_t)(m0 + r) * K + (k0 + 32) + c];
                bR[jj] = *(const uint4*)&Bt[(size_t)(n0 + r) * K + (k0 + 32) + c];
            }
        }
        __syncthreads();
        short8 af[4], bfr[4];
#pragma unroll
        for (int mt = 0; mt < 4; mt++) af[mt] = *(short8*)&As[wr * 64 + mt * 16 + l16][quad * 8];
#pragma unroll
        for (int nt = 0; nt < 4; nt++) bfr[nt] = *(short8*)&Bs[wc * 64 + nt * 16 + l16][quad * 8];
#pragma unroll
        for (int mt = 0; mt < 4; mt++)
#pragma unroll
            for (int nt = 0; nt < 4; nt++) acc[mt][nt] = MFMA16(af[mt], bfr[nt], acc[mt][nt]);
    }

    // Epilogue [verified R5-R10]
#pragma unroll
    for (int nt = 0; nt < 4; nt++) {
        const int n = n0 + wc * 64 + nt * 16 + l16;
        const int seg = n >> 10;          // 0=q 1=k 2=v
        const int cn = n & 1023;
        const int h = cn >> 6, d = cn & 63;
#pragma unroll
        for (int mt = 0; mt < 4; mt++) {
#pragma unroll
            for (int r = 0; r < 4; r++) {
                const int t = m0 + wr * 64 + mt * 16 + quad * 4 + r;
                const ushort v = f2bf(acc[mt][nt][r]);
                if (seg == 0)      qb[((size_t)h * 2048 + t) * 64 + d] = v;
                else if (seg == 1) kb[((size_t)h * 2048 + t) * 64 + d] = v;
                else               vtb[((size_t)h * 64 + d) * 2048 + t] = v;
            }
        }
    }
}

// ---------------------------------------------------------------------------
// RoPE (roll variant), f64 trig  [verified R5-R10]
// ---------------------------------------------------------------------------
__global__ __launch_bounds__(256) void rope_k(ushort* __restrict__ q, ushort* __restrict__ k) {
    const int wid = blockIdx.x * 4 + (threadIdx.x >> 6);  // row = h*2048 + t
    const int lane = threadIdx.x & 63;
    const int t = wid & 2047;
    const int j = lane & 31;
    const double inv = pow(10000.0, -(double)j / 32.0);
    const double ang = (double)t * inv;
    const float c = (float)cos(ang);
    const float s = (float)sin(ang);
    const size_t base = (size_t)wid * 64;

    float qv = bf2f(q[base + lane]);
    float qp = __shfl(qv, (lane + 63) & 63, 64);
    q[base + lane] = f2bf(qv * c + qp * s);

    float kv = bf2f(k[base + lane]);
    float kp = __shfl(kv, (lane + 63) & 63, 64);
    k[base + lane] = f2bf(kv * c + kp * s);
}

// ---------------------------------------------------------------------------
// Flash attention (causal), transposed form  [verified R10 — unchanged]
// ---------------------------------------------------------------------------
__global__ __launch_bounds__(256, 2) void attn_k(const ushort* __restrict__ q,
                                                 const ushort* __restrict__ k,
                                                 const ushort* __restrict__ vt,
                                                 ushort* __restrict__ y) {
    __shared__ __align__(16) ushort Ks[64][72];    // [key][d]  bf16
    __shared__ __align__(16) ushort Vs[64][72];    // [d][key]  bf16 (V^T)
    __shared__ __align__(16) ushort Ps[4][16][72]; // per-wave P^T as [qrow][key]

    const int p = blockIdx.x & 15;
    const int h = blockIdx.x >> 4;
    const int tid = threadIdx.x, w = tid >> 6, lane = tid & 63;
    const int quad = lane >> 4, l16 = lane & 15;

    for (int phase = 0; phase < 2; phase++) {
        const int qt = phase ? (31 - p) : p;
        const int q0 = qt * 64;
        const int qrow = q0 + w * 16 + l16;

        short8 qa0, qa1;
        {
            const ushort* qp = q + ((size_t)h * 2048 + qrow) * 64 + quad * 8;
            qa0 = *(const short8*)(qp);
            qa1 = *(const short8*)(qp + 32);
        }

        floatx4 O[4];
#pragma unroll
        for (int dt = 0; dt < 4; dt++) O[dt] = (floatx4){0.f, 0.f, 0.f, 0.f};
        float M = -30000.f, L = 0.f;

        for (int kt = 0; kt <= qt; kt++) {
            const int kbase = kt * 64;
            __syncthreads();
#pragma unroll
            for (int jj = 0; jj < 2; jj++) {
                int flat = (tid + jj * 256) * 8;
                int r = flat >> 6, c = flat & 63;
                *(uint4*)&Ks[r][c] = *(const uint4*)&k[((size_t)h * 2048 + kbase + r) * 64 + c];
                *(uint4*)&Vs[r][c] = *(const uint4*)&vt[((size_t)h * 64 + r) * 2048 + kbase + c];
            }
            __syncthreads();

            floatx4 s[4];
#pragma unroll
            for (int nt = 0; nt < 4; nt++) {
                short8 ka0 = *(short8*)&Ks[nt * 16 + l16][quad * 8];
                short8 ka1 = *(short8*)&Ks[nt * 16 + l16][32 + quad * 8];
                floatx4 z = (floatx4){0.f, 0.f, 0.f, 0.f};
                z = MFMA16(ka0, qa0, z);
                z = MFMA16(ka1, qa1, z);
                s[nt] = z;
            }

            const bool diag = (kt == qt);
#pragma unroll
            for (int nt = 0; nt < 4; nt++)
#pragma unroll
                for (int r = 0; r < 4; r++) {
                    float vv = s[nt][r] * 0.125f;
                    if (diag) {
                        const int kidx = kbase + nt * 16 + quad * 4 + r;
                        if (kidx > qrow) vv = -30000.f;
                    }
                    s[nt][r] = vv;
                }

            float mx = -30000.f;
#pragma unroll
            for (int nt = 0; nt < 4; nt++)
#pragma unroll
                for (int r = 0; r < 4; r++) mx = fmaxf(mx, s[nt][r]);
            mx = fmaxf(mx, __shfl_xor(mx, 16, 64));
            mx = fmaxf(mx, __shfl_xor(mx, 32, 64));
            const float Mn = fmaxf(M, mx);
            const float alpha = __expf(M - Mn);
            float sum = 0.f;
#pragma unroll
            for (int nt = 0; nt < 4; nt++)
#pragma unroll
                for (int r = 0; r < 4; r++) {
                    float pv = __expf(s[nt][r] - Mn);
                    s[nt][r] = pv;
                    sum += pv;
                }
            sum += __shfl_xor(sum, 16, 64);
            sum += __shfl_xor(sum, 32, 64);
            L = L * alpha + sum;
            M = Mn;
#pragma unroll
            for (int dt = 0; dt < 4; dt++) O[dt] *= alpha;

#pragma unroll
            for (int nt = 0; nt < 4; nt++) {
                ushort4 pk = make_ushort4(f2bf(s[nt][0]), f2bf(s[nt][1]),
                                          f2bf(s[nt][2]), f2bf(s[nt][3]));
                *(ushort4*)&Ps[w][l16][nt * 16 + quad * 4] = pk;
            }
            __syncthreads();

            short8 pb0 = *(short8*)&Ps[w][l16][quad * 8];
            short8 pb1 = *(short8*)&Ps[w][l16][32 + quad * 8];
#pragma unroll
            for (int dt = 0; dt < 4; dt++) {
                short8 va0 = *(short8*)&Vs[dt * 16 + l16][quad * 8];
                short8 va1 = *(short8*)&Vs[dt * 16 + l16][32 + quad * 8];
                O[dt] = MFMA16(va0, pb0, O[dt]);
                O[dt] = MFMA16(va1, pb1, O[dt]);
            }
        }

        const float rl = 1.0f / L;
#pragma unroll
        for (int dt = 0; dt < 4; dt++) {
            ushort4 o4 = make_ushort4(f2bf(O[dt][0] * rl), f2bf(O[dt][1] * rl),
                                      f2bf(O[dt][2] * rl), f2bf(O[dt][3] * rl));
            *(ushort4*)&y[(size_t)qrow * 1024 + h * 64 + dt * 16 + quad * 4] = o4;
        }
    }
}

// ---------------------------------------------------------------------------
// GEMM2 (one batch): out(f32) = y[2048][1024](bf16) @ WpT^T (bf16 [1024][1024])
// 64x128 tile, pure uint4 staging, register prefetch.
// ---------------------------------------------------------------------------
__global__ __launch_bounds__(256, 2) void gemm2_proj_k(const ushort* __restrict__ Y,
                                                       const ushort* __restrict__ Bt,
                                                       float* __restrict__ out) {
    __shared__ __align__(16) ushort As[64][40];    // [m][k]
    __shared__ __align__(16) ushort Bs[128][40];   // [n][k]
    const int tid = threadIdx.x;
    const int m0 = blockIdx.y * 64, n0 = blockIdx.x * 128;
    const int w = tid >> 6, lane = tid & 63, quad = lane >> 4, l16 = lane & 15;
    const int wr = w >> 1, wc = w & 1;
    const int K = 1024;

    floatx4 acc[2][4];
#pragma unroll
    for (int mt = 0; mt < 2; mt++)
#pragma unroll
        for (int nt = 0; nt < 4; nt++) acc[mt][nt] = (floatx4){0.f, 0.f, 0.f, 0.f};

    uint4 aR, bR[2];
    {
        int flat = tid * 8;
        aR = *(const uint4*)&Y[(size_t)(m0 + (flat >> 5)) * K + (flat & 31)];
#pragma unroll
        for (int jj = 0; jj < 2; jj++) {
            int f2 = (tid + jj * 256) * 8;
            bR[jj] = *(const uint4*)&Bt[(size_t)(n0 + (f2 >> 5)) * K + (f2 & 31)];
        }
    }

    for (int k0 = 0; k0 < K; k0 += 32) {
        __syncthreads();
        {
            int flat = tid * 8;
            *(uint4*)&As[flat >> 5][flat & 31] = aR;
#pragma unroll
            for (int jj = 0; jj < 2; jj++) {
                int f2 = (tid + jj * 256) * 8;
                *(uint4*)&Bs[f2 >> 5][f2 & 31] = bR[jj];
            }
        }
        if (k0 + 32 < K) {
            int flat = tid * 8;
            aR = *(const uint4*)&Y[(size_t)(m0 + (flat >> 5)) * K + (k0 + 32) + (flat & 31)];
#pragma unroll
            for (int jj = 0; jj < 2; jj++) {
                int f2 = (tid + jj * 256) * 8;
                bR[jj] = *(const uint4*)&Bt[(size_t)(n0 + (f2 >> 5)) * K + (k0 + 32) + (f2 & 31)];
            }
        }
        __syncthreads();
        short8 af[2], bfr[4];
#pragma unroll
        for (int mt = 0; mt < 2; mt++) af[mt] = *(short8*)&As[wr * 32 + mt * 16 + l16][quad * 8];
#pragma unroll
        for (int nt = 0; nt < 4; nt++) bfr[nt] = *(short8*)&Bs[wc * 64 + nt * 16 + l16][quad * 8];
#pragma unroll
        for (int mt = 0; mt < 2; mt++)
#pragma unroll
            for (int nt = 0; nt < 4; nt++) acc[mt][nt] = MFMA16(af[mt], bfr[nt], acc[mt][nt]);
    }

#pragma unroll
    for (int mt = 0; mt < 2; mt++)
#pragma unroll
        for (int nt = 0; nt < 4; nt++) {
            const int n = n0 + wc * 64 + nt * 16 + l16;
#pragma unroll
            for (int r = 0; r < 4; r++) {
                const int m = m0 + wr * 32 + mt * 16 + quad * 4 + r;
                out[(size_t)m * 1024 + n] = acc[mt][nt][r];
            }
        }
}

// ---------------------------------------------------------------------------
extern "C" void kernel_launch(void* const* d_in, const int* in_sizes, int n_in,
                              void* d_out, int out_size, void* d_ws, size_t ws_size,
                              hipStream_t stream) {
    const float* x  = (const float*)d_in[0];   // [2,2048,1024] f32
    const float* Wa = (const float*)d_in[1];   // [1024,3072]  f32
    const float* Wp = (const float*)d_in[2];   // [1024,1024]  f32
    float* out = (float*)d_out;                // [2,2048,1024] f32

    const size_t PB = (size_t)2048 * 1024;     // per-batch elements
    ushort* qb  = (ushort*)d_ws;               // 4 MB bf16 q  [H,T,HD]
    ushort* kb  = qb + PB;                     // 4 MB bf16 k  [H,T,HD]
    ushort* vtb = kb + PB;                     // 4 MB bf16 v^T[H,HD,T]
    ushort* yb  = vtb + PB;                    // 4 MB bf16 y [T,C] / x_bf16
    ushort* wtA = (ushort*)(out + PB);         // 6 MB W_attn^T bf16 (d_out b1
                                               //  half; dead until gemm2-b1,
                                               //  which fully overwrites it)
    ushort* wtP = qb;                          // 2 MB W_proj^T bf16 (qb slot,
                                               //  dead after attn each batch)

    tp_k<<<dim3(96, 32), 256, 0, stream>>>(Wa, wtA, 1024, 3072);
    for (int b = 0; b < 2; b++) {
        cvt_k<<<dim3(2048), 256, 0, stream>>>(x + b * PB, yb);        // xb in yb slot
        gemm1_qkv_k<<<dim3(24, 16), 256, 0, stream>>>(yb, wtA, qb, kb, vtb);
        rope_k<<<dim3(8192), 256, 0, stream>>>(qb, kb);
        attn_k<<<dim3(256), 256, 0, stream>>>(qb, kb, vtb, yb);       // y over xb
        tp_k<<<dim3(32, 32), 256, 0, stream>>>(Wp, wtP, 1024, 1024);  // over dead q
        gemm2_proj_k<<<dim3(8, 32), 256, 0, stream>>>(yb, wtP, out + b * PB);
    }
}